// Round 6
// baseline (413.940 us; speedup 1.0000x reference)
//
#include <hip/hip_runtime.h>
#include <hip/hip_fp16.h>
#include <stdint.h>

typedef unsigned long long u64;
typedef _Float16 half8 __attribute__((ext_vector_type(8)));
typedef float f32x4 __attribute__((ext_vector_type(4)));

__device__ __forceinline__ float sigm(float x) { return 1.0f / (1.0f + __expf(-x)); }
__device__ __forceinline__ float tanhfast(float x) { return 1.0f - 2.0f / (__expf(2.0f * x) + 1.0f); }
__device__ __forceinline__ int rli(int v, int k) { return __builtin_amdgcn_readlane(v, k); }
__device__ __forceinline__ float rlf(float v, int k) {
    return __int_as_float(__builtin_amdgcn_readlane(__float_as_int(v), k));
}

// Zero cntdeg + gcur (separate dispatch: k_prec's count atomics need it done first;
// no host-side memset APIs in the launch path -> graph-capture safe by construction).
__global__ void k_zero(u64* __restrict__ cntdeg, int* __restrict__ gcur, int n) {
    int i = blockIdx.x * 256 + threadIdx.x;
    if (i < n) cntdeg[i] = 0ULL;
    if (i < 16) gcur[i] = 0;
}

// Fused: fragment-packed weight build (blocks 0..112) + h->fp16 (blocks 113..113+hb)
// + per-edge count/degree atomics (remaining blocks).
// cntdeg[d] += (1<<48) | (u64)(w * 2^32): count in [63:48], weighted degree as
// 48-bit fixed point below (sum < 2^38, never carries into count bits).
__global__ void k_prec(const float* __restrict__ Wcz, const float* __restrict__ bcz,
                       const float* __restrict__ Wcr, const float* __restrict__ bcr,
                       const float* __restrict__ Wch, const float* __restrict__ bch,
                       const float* __restrict__ Wlz, const float* __restrict__ blz,
                       const float* __restrict__ Wlr, const float* __restrict__ blr,
                       const float* __restrict__ Wlh, const float* __restrict__ blh,
                       const float4* __restrict__ h4, __half* __restrict__ aggh,
                       __half* __restrict__ B1f, __half* __restrict__ B2f,
                       float* __restrict__ bias,
                       const int* __restrict__ dst, const float* __restrict__ ew,
                       u64* __restrict__ cntdeg, int hq, int E, int hb) {
    int bid = blockIdx.x;
    if (bid < 113) {
        int tid = bid * 256 + threadIdx.x;
        if (tid < 24576) {
            int k = tid / 192, nc = tid % 192;
            int g = nc >> 6, j = nc & 63;
            const float* Wc = (g == 0) ? Wcz : (g == 1) ? Wcr : Wch;
            const float* Wl = (g == 0) ? Wlz : (g == 1) ? Wlr : Wlh;
            float v;
            if (k < 64) {
                float acc = 0.f;
                for (int m = 0; m < 64; m++) acc += Wc[k * 64 + m] * Wl[m * 64 + j];
                v = acc;
            } else {
                v = (g < 2) ? Wl[k * 64 + j] : 0.f;
            }
            int kt = k >> 5, nt = nc >> 4;
            int lane = (((k >> 3) & 3) << 4) | (nc & 15);
            B1f[(((kt * 12 + nt) * 64 + lane) << 3) + (k & 7)] = (__half)v;
        } else if (tid < 24576 + 4096) {
            int t = tid - 24576;
            int k = t >> 6, nc = t & 63;
            float v = Wlh[(64 + k) * 64 + nc];
            int kt = k >> 5, nt = nc >> 4;
            int lane = (((k >> 3) & 3) << 4) | (nc & 15);
            B2f[(((kt * 4 + nt) * 64 + lane) << 3) + (k & 7)] = (__half)v;
        } else if (tid < 24576 + 4096 + 192) {
            int t = tid - 24576 - 4096;
            int g = t >> 6, j = t & 63;
            const float* bc = (g == 0) ? bcz : (g == 1) ? bcr : bch;
            const float* Wl = (g == 0) ? Wlz : (g == 1) ? Wlr : Wlh;
            const float* bl = (g == 0) ? blz : (g == 1) ? blr : blh;
            float acc = bl[j];
            for (int m = 0; m < 64; m++) acc += bc[m] * Wl[m * 64 + j];
            bias[t] = acc;
        }
    } else if (bid < 113 + hb) {
        int i = (bid - 113) * 256 + threadIdx.x;
        if (i < hq) {
            float4 hv = h4[i];
            int elem = i * 4;
            int node = elem >> 6, c = elem & 63;
            __half2* ho = (__half2*)(aggh + (((size_t)node) << 7) + 64 + c);
            ho[0] = __floats2half2_rn(hv.x, hv.y);
            ho[1] = __floats2half2_rn(hv.z, hv.w);
        }
    } else {
        int e = (bid - 113 - hb) * 256 + threadIdx.x;
        if (e < E) {
            int d = dst[e];
            float w = ew[e];
            atomicAdd(&cntdeg[d], (1ULL << 48) | (u64)(w * 4294967296.0f));
        }
    }
}

// Block-scan of 1024 node counts -> CSR offsets (block base via one global
// atomic: regions only need to be disjoint, allocation order is irrelevant).
// Also: dinv = rsqrt(1+deg) and xs = dinv*x in fp16 (absorbed from old k_sort).
__global__ void __launch_bounds__(1024) k_scan(const u64* __restrict__ cntdeg,
                                               const float2* __restrict__ x2,
                                               int* __restrict__ off_g, int* __restrict__ len_g,
                                               int* __restrict__ cur_g, float* __restrict__ dinv,
                                               __half2* __restrict__ xs2,
                                               int* __restrict__ gcur, int n) {
    __shared__ int wsum[16];
    __shared__ int sbase;
    __shared__ float dvS[1024];

    int tid = threadIdx.x;
    int nb = blockIdx.x * 1024;
    int node = nb + tid;
    u64 v = (node < n) ? cntdeg[node] : 0ULL;
    int c = (int)(v >> 48);
    float deg = (float)(v & 0xFFFFFFFFFFFFULL) * 0x1p-32f;

    int lane = tid & 63, wv = tid >> 6;
    int scan = c;
#pragma unroll
    for (int o = 1; o < 64; o <<= 1) {
        int t = __shfl_up(scan, o);
        if (lane >= o) scan += t;
    }
    if (lane == 63) wsum[wv] = scan;
    __syncthreads();
    if (tid < 16) {
        int s = wsum[tid];
        int sc = s;
#pragma unroll
        for (int o = 1; o < 16; o <<= 1) {
            int t = __shfl_up(sc, o);
            if (tid >= o) sc += t;
        }
        wsum[tid] = sc - s;                    // exclusive wave offset
        if (tid == 15) sbase = atomicAdd(gcur, sc);   // sc == block total
    }
    __syncthreads();

    int excl = (scan - c) + wsum[wv] + sbase;
    float dv = rsqrtf(1.0f + deg);
    if (node < n) {
        off_g[node] = excl;
        cur_g[node] = excl;
        len_g[node] = c;
        dinv[node]  = dv;
    }
    dvS[tid] = dv;
    __syncthreads();

    // xs build: 1024 nodes x 32 float2 = 32768 items
    for (int i = tid; i < 1024 * 32; i += 1024) {
        int nl = i >> 5, cp = i & 31;
        int nd = nb + nl;
        if (nd < n) {
            float2 xv = x2[((size_t)nd << 5) + cp];
            float d2 = dvS[nl];
            xs2[((size_t)nd << 5) + cp] = __floats2half2_rn(d2 * xv.x, d2 * xv.y);
        }
    }
}

// Ticket-scatter edges straight into the compact CSR. rec: [63:32]=ew, [16:0]=src.
__global__ void __launch_bounds__(1024) k_scatter(const int* __restrict__ src,
                                                  const int* __restrict__ dst,
                                                  const float* __restrict__ ew,
                                                  int* __restrict__ cur_g,
                                                  u64* __restrict__ csr, int E) {
    int e = blockIdx.x * 1024 + threadIdx.x;
    if (e >= E) return;
    int s = src[e], d = dst[e];
    float w = ew[e];
    int slot = atomicAdd(&cur_g[d], 1);
    csr[slot] = (u64)(unsigned)s | ((u64)__float_as_uint(w) << 32);
}

// wave per node over CSR runs: agg = dd * (xs[d] + sum ew*xs[src]); ILP-16
// (exact round-0 structure: proven best across 3 restructure attempts)
__global__ void __launch_bounds__(256) k_gather(const int* __restrict__ off_g, const int* __restrict__ len_g,
                                                const u64* __restrict__ csr, const float* __restrict__ dinv,
                                                const __half* __restrict__ xs,
                                                __half* __restrict__ aggh, int n) {
    int lane = threadIdx.x & 63;
    int wid = __builtin_amdgcn_readfirstlane(threadIdx.x >> 6);
    int d = blockIdx.x * 4 + wid;
    if (d >= n) return;
    int o0 = off_g[d], L = len_g[d];
    float dd = dinv[d];
    float acc[16];
#pragma unroll
    for (int j = 0; j < 16; j++) acc[j] = 0.f;
    acc[0] = (float)xs[((size_t)d << 6) + lane];   // self term (weight 1 in scaled space)

    for (int base = 0; base < L; base += 64) {
        int c = min(64, L - base);
        u64 m = (lane < c) ? csr[(size_t)(o0 + base) + lane] : 0;
        int s_l = (unsigned)m & 0x1FFFF;
        float w_l = __uint_as_float((unsigned)(m >> 32));
        int k = 0;
        for (; k + 16 <= c; k += 16) {
            int ss[16]; float ww[16], xr[16];
#pragma unroll
            for (int j = 0; j < 16; j++) { ss[j] = rli(s_l, k + j); ww[j] = rlf(w_l, k + j); }
#pragma unroll
            for (int j = 0; j < 16; j++) xr[j] = (float)xs[((size_t)ss[j] << 6) + lane];
#pragma unroll
            for (int j = 0; j < 16; j++) acc[j] = fmaf(ww[j], xr[j], acc[j]);
        }
        for (; k + 4 <= c; k += 4) {
            int ss[4]; float ww[4], xr[4];
#pragma unroll
            for (int j = 0; j < 4; j++) { ss[j] = rli(s_l, k + j); ww[j] = rlf(w_l, k + j); }
#pragma unroll
            for (int j = 0; j < 4; j++) xr[j] = (float)xs[((size_t)ss[j] << 6) + lane];
#pragma unroll
            for (int j = 0; j < 4; j++) acc[j] = fmaf(ww[j], xr[j], acc[j]);
        }
        for (; k < c; k++) {
            int s0 = rli(s_l, k);
            float w0 = rlf(w_l, k);
            acc[0] = fmaf(w0, (float)xs[((size_t)s0 << 6) + lane], acc[0]);
        }
    }
    float s = ((acc[0] + acc[1]) + (acc[2] + acc[3])) + ((acc[4] + acc[5]) + (acc[6] + acc[7]))
            + ((acc[8] + acc[9]) + (acc[10] + acc[11])) + ((acc[12] + acc[13]) + (acc[14] + acc[15]));
    aggh[((size_t)d << 7) + lane] = (__half)(dd * s);
}

// MFMA gate kernel (body unchanged, known-good); grid = one 64-node group per block
__global__ void __launch_bounds__(256, 2) k_node(
        const __half* __restrict__ aggh,
        const __half* __restrict__ B1f_g, const __half* __restrict__ B2f_g,
        const float* __restrict__ bias_g, const float* __restrict__ Whead,
        const float* __restrict__ bhead,
        float* __restrict__ out_head, float* __restrict__ out_h, int n) {

    __shared__ __half B1s[24576];
    __shared__ __half B2s[4096];
    __shared__ float biasS[192];
    __shared__ float whS[64];
    __shared__ __half hrb[4][16 * 72];

    int tid = threadIdx.x;
    {
        const uint4* s1 = (const uint4*)B1f_g; uint4* d1 = (uint4*)B1s;
        for (int i = tid; i < 3072; i += 256) d1[i] = s1[i];
        const uint4* s2 = (const uint4*)B2f_g; uint4* d2 = (uint4*)B2s;
        for (int i = tid; i < 512; i += 256) d2[i] = s2[i];
        if (tid < 192) biasS[tid] = bias_g[tid];
        if (tid < 64) whS[tid] = Whead[tid];
    }
    __syncthreads();

    int lane = tid & 63;
    int wave = tid >> 6;
    int quad = lane >> 4;
    int l15 = lane & 15;

    float bz4[4], br4[4], bh4[4], wh4[4];
#pragma unroll
    for (int nt = 0; nt < 4; nt++) {
        bz4[nt] = biasS[nt * 16 + l15];
        br4[nt] = biasS[64 + nt * 16 + l15];
        bh4[nt] = biasS[128 + nt * 16 + l15];
        wh4[nt] = whS[nt * 16 + l15];
    }
    float bhv = bhead[0];
    __half* myhr = &hrb[wave][0];
    const half8* B1v = (const half8*)B1s;
    const half8* B2v = (const half8*)B2s;

    int mbase = blockIdx.x * 64 + wave * 16;
    if (mbase < n) {
        const half8* arow = (const half8*)(aggh + (((size_t)(mbase + l15)) << 7) + (quad << 3));
        half8 a0 = arow[0], a1 = arow[4], a2 = arow[8], a3 = arow[12];

        f32x4 acc[12];
#pragma unroll
        for (int nt = 0; nt < 12; nt++) acc[nt] = (f32x4){0.f, 0.f, 0.f, 0.f};

#pragma unroll
        for (int nt = 0; nt < 12; nt++) {
            acc[nt] = __builtin_amdgcn_mfma_f32_16x16x32_f16(a0, B1v[(0 * 12 + nt) * 64 + lane], acc[nt], 0, 0, 0);
            acc[nt] = __builtin_amdgcn_mfma_f32_16x16x32_f16(a1, B1v[(1 * 12 + nt) * 64 + lane], acc[nt], 0, 0, 0);
            acc[nt] = __builtin_amdgcn_mfma_f32_16x16x32_f16(a2, B1v[(2 * 12 + nt) * 64 + lane], acc[nt], 0, 0, 0);
            acc[nt] = __builtin_amdgcn_mfma_f32_16x16x32_f16(a3, B1v[(3 * 12 + nt) * 64 + lane], acc[nt], 0, 0, 0);
        }

        float hv[4][4];
#pragma unroll
        for (int nt = 0; nt < 4; nt++)
#pragma unroll
            for (int r = 0; r < 4; r++)
                hv[nt][r] = (float)aggh[(((size_t)(mbase + quad * 4 + r)) << 7) + 64 + nt * 16 + l15];

        float Z[4][4];
#pragma unroll
        for (int nt = 0; nt < 4; nt++)
#pragma unroll
            for (int r = 0; r < 4; r++) {
                Z[nt][r] = sigm(acc[nt][r] + bz4[nt]);
                float R = sigm(acc[4 + nt][r] + br4[nt]);
                myhr[(quad * 4 + r) * 72 + nt * 16 + l15] = (__half)(hv[nt][r] * R);
            }
        __builtin_amdgcn_s_waitcnt(0);

        half8 a2f0 = *(const half8*)(myhr + l15 * 72 + quad * 8);
        half8 a2f1 = *(const half8*)(myhr + l15 * 72 + 32 + quad * 8);

#pragma unroll
        for (int nt = 0; nt < 4; nt++) {
            acc[8 + nt] = __builtin_amdgcn_mfma_f32_16x16x32_f16(a2f0, B2v[(0 * 4 + nt) * 64 + lane], acc[8 + nt], 0, 0, 0);
            acc[8 + nt] = __builtin_amdgcn_mfma_f32_16x16x32_f16(a2f1, B2v[(1 * 4 + nt) * 64 + lane], acc[8 + nt], 0, 0, 0);
        }

        float pr0 = 0.f, pr1 = 0.f, pr2 = 0.f, pr3 = 0.f;
#pragma unroll
        for (int nt = 0; nt < 4; nt++) {
#pragma unroll
            for (int r = 0; r < 4; r++) {
                float Ht = tanhfast(acc[8 + nt][r] + bh4[nt]);
                float z = Z[nt][r];
                float hn = z * hv[nt][r] + (1.f - z) * Ht;
                out_h[((size_t)(mbase + quad * 4 + r)) * 64 + nt * 16 + l15] = hn;
                float rv = fmaxf(hn, 0.f) * wh4[nt];
                if (r == 0) pr0 += rv; else if (r == 1) pr1 += rv; else if (r == 2) pr2 += rv; else pr3 += rv;
            }
        }
#pragma unroll
        for (int o = 1; o < 16; o <<= 1) {
            pr0 += __shfl_xor(pr0, o);
            pr1 += __shfl_xor(pr1, o);
            pr2 += __shfl_xor(pr2, o);
            pr3 += __shfl_xor(pr3, o);
        }
        if (l15 == 0) {
            out_head[mbase + quad * 4 + 0] = pr0 + bhv;
            out_head[mbase + quad * 4 + 1] = pr1 + bhv;
            out_head[mbase + quad * 4 + 2] = pr2 + bhv;
            out_head[mbase + quad * 4 + 3] = pr3 + bhv;
        }
    }
}

extern "C" void kernel_launch(void* const* d_in, const int* in_sizes, int n_in,
                              void* d_out, int out_size, void* d_ws, size_t ws_size,
                              hipStream_t stream) {
    const float* x     = (const float*)d_in[0];
    const int*   src   = (const int*)d_in[1];
    const int*   dst   = (const int*)d_in[2];
    const float* ew    = (const float*)d_in[3];
    const float* h     = (const float*)d_in[4];
    const float* Wcz   = (const float*)d_in[5];
    const float* bcz   = (const float*)d_in[6];
    const float* Wcr   = (const float*)d_in[7];
    const float* bcr   = (const float*)d_in[8];
    const float* Wch   = (const float*)d_in[9];
    const float* bch   = (const float*)d_in[10];
    const float* Wlz   = (const float*)d_in[11];
    const float* blz   = (const float*)d_in[12];
    const float* Wlr   = (const float*)d_in[13];
    const float* blr   = (const float*)d_in[14];
    const float* Wlh   = (const float*)d_in[15];
    const float* blh   = (const float*)d_in[16];
    const float* Whead = (const float*)d_in[17];
    const float* bhead = (const float*)d_in[18];

    int E = in_sizes[1];
    int n = in_sizes[4] / 64;                 // 100000 nodes

    // workspace layout
    __half* aggh = (__half*)d_ws;                        // n*128 fp16: [agg | h]
    __half* xs   = aggh + (size_t)n * 128;               // n*64 fp16 (dinv-scaled x)
    u64*   csr   = (u64*)(xs + (size_t)n * 64);          // E u64 (compact CSR)
    u64*   cntdeg = csr + (size_t)E;                     // n u64 (count<<48 | deg fixpt)
    int*   gcur  = (int*)(cntdeg + n);                   // 16 ints (pad)
    int*   off_g = gcur + 16;                            // n
    int*   len_g = off_g + n;                            // n
    int*   cur_g = len_g + n;                            // n
    float* dinv  = (float*)(cur_g + n);                  // n
    __half* B1f  = (__half*)(dinv + n);                  // 24576 fp16
    __half* B2f  = B1f + 24576;                          // 4096 fp16
    float* bias  = (float*)(B2f + 4096);                 // 192 f32

    float* out_head = (float*)d_out;          // [n]
    float* out_h    = out_head + n;           // [n*64]

    int hq = n * 16;                          // float4 groups of h
    int hb = (hq + 255) / 256;
    int eb = (E + 255) / 256;

    k_zero<<<(n + 255) / 256, 256, 0, stream>>>(cntdeg, gcur, n);
    k_prec<<<113 + hb + eb, 256, 0, stream>>>(Wcz, bcz, Wcr, bcr, Wch, bch,
                                              Wlz, blz, Wlr, blr, Wlh, blh,
                                              (const float4*)h, aggh, B1f, B2f, bias,
                                              dst, ew, cntdeg, hq, E, hb);
    k_scan<<<(n + 1023) / 1024, 1024, 0, stream>>>(cntdeg, (const float2*)x,
                                                   off_g, len_g, cur_g, dinv,
                                                   (__half2*)xs, gcur, n);
    k_scatter<<<(E + 1023) / 1024, 1024, 0, stream>>>(src, dst, ew, cur_g, csr, E);
    k_gather<<<(n + 3) / 4, 256, 0, stream>>>(off_g, len_g, csr, dinv, xs, aggh, n);
    k_node<<<(n + 63) / 64, 256, 0, stream>>>(aggh, B1f, B2f, bias, Whead, bhead,
                                              out_head, out_h, n);
}

// Round 7
// 250.180 us; speedup vs baseline: 1.6546x; 1.6546x over previous
//
#include <hip/hip_runtime.h>
#include <hip/hip_fp16.h>
#include <stdint.h>

typedef unsigned long long u64;
typedef _Float16 half8 __attribute__((ext_vector_type(8)));
typedef float f32x4 __attribute__((ext_vector_type(4)));

#define EPB 6144      // edges staged per k_bin block
#define CAPC 5440     // bucket capacity (mean 4096 + huge margin)

__device__ __forceinline__ float sigm(float x) { return 1.0f / (1.0f + __expf(-x)); }
__device__ __forceinline__ float tanhfast(float x) { return 1.0f - 2.0f / (__expf(2.0f * x) + 1.0f); }
__device__ __forceinline__ int rli(int v, int k) { return __builtin_amdgcn_readlane(v, k); }
__device__ __forceinline__ float rlf(float v, int k) {
    return __int_as_float(__builtin_amdgcn_readlane(__float_as_int(v), k));
}

// Merged: fragment-packed weight build (blocks 0..112) + h->fp16 (blocks 113..) + cursor zero.
__global__ void k_pre(const float* __restrict__ Wcz, const float* __restrict__ bcz,
                      const float* __restrict__ Wcr, const float* __restrict__ bcr,
                      const float* __restrict__ Wch, const float* __restrict__ bch,
                      const float* __restrict__ Wlz, const float* __restrict__ blz,
                      const float* __restrict__ Wlr, const float* __restrict__ blr,
                      const float* __restrict__ Wlh, const float* __restrict__ blh,
                      const float4* __restrict__ h4, __half* __restrict__ aggh,
                      __half* __restrict__ B1f, __half* __restrict__ B2f,
                      float* __restrict__ bias, int* __restrict__ cursor, int hq) {
    int bid = blockIdx.x;
    if (bid < 113) {
        int tid = bid * 256 + threadIdx.x;
        if (tid < 1024) cursor[tid] = 0;
        if (tid < 24576) {
            int k = tid / 192, nc = tid % 192;
            int g = nc >> 6, j = nc & 63;
            const float* Wc = (g == 0) ? Wcz : (g == 1) ? Wcr : Wch;
            const float* Wl = (g == 0) ? Wlz : (g == 1) ? Wlr : Wlh;
            float v;
            if (k < 64) {
                float acc = 0.f;
                for (int m = 0; m < 64; m++) acc += Wc[k * 64 + m] * Wl[m * 64 + j];
                v = acc;
            } else {
                v = (g < 2) ? Wl[k * 64 + j] : 0.f;
            }
            int kt = k >> 5, nt = nc >> 4;
            int lane = (((k >> 3) & 3) << 4) | (nc & 15);
            B1f[(((kt * 12 + nt) * 64 + lane) << 3) + (k & 7)] = (__half)v;
        } else if (tid < 24576 + 4096) {
            int t = tid - 24576;
            int k = t >> 6, nc = t & 63;
            float v = Wlh[(64 + k) * 64 + nc];
            int kt = k >> 5, nt = nc >> 4;
            int lane = (((k >> 3) & 3) << 4) | (nc & 15);
            B2f[(((kt * 4 + nt) * 64 + lane) << 3) + (k & 7)] = (__half)v;
        } else if (tid < 24576 + 4096 + 192) {
            int t = tid - 24576 - 4096;
            int g = t >> 6, j = t & 63;
            const float* bc = (g == 0) ? bcz : (g == 1) ? bcr : bch;
            const float* Wl = (g == 0) ? Wlz : (g == 1) ? Wlr : Wlh;
            const float* bl = (g == 0) ? blz : (g == 1) ? blr : blh;
            float acc = bl[j];
            for (int m = 0; m < 64; m++) acc += bc[m] * Wl[m * 64 + j];
            bias[t] = acc;
        }
    } else {
        int i = (bid - 113) * 256 + threadIdx.x;
        if (i < hq) {
            float4 hv = h4[i];
            int elem = i * 4;
            int node = elem >> 6, c = elem & 63;
            __half2* ho = (__half2*)(aggh + (((size_t)node) << 7) + 64 + c);
            ho[0] = __floats2half2_rn(hv.x, hv.y);
            ho[1] = __floats2half2_rn(hv.z, hv.w);
        }
    }
}

// One-pass LDS-staged counting sort of edges into 256-node dst-buckets.
// rec u64: [63:32]=ew bits, [24:17]=dst&255, [16:0]=src
__global__ void __launch_bounds__(1024) k_bin(const int* __restrict__ src, const int* __restrict__ dst,
                                              const float* __restrict__ ew,
                                              int* __restrict__ cursor, u64* __restrict__ binned,
                                              int E, int R) {
    __shared__ u64 recs[EPB];        // 48 KB
    __shared__ int hist[512];
    __shared__ int loff[512];
    __shared__ int curL[512];
    __shared__ int gbase[512];

    int tid = threadIdx.x;
    if (tid < 512) hist[tid] = 0;
    __syncthreads();

    int base = blockIdx.x * EPB;
    int cntE = min(EPB, E - base);

    u64 myrec[6];
    int myr[6];
#pragma unroll
    for (int j = 0; j < 6; j++) {
        int idx = tid + j * 1024;
        if (idx < cntE) {
            int e = base + idx;
            int d = dst[e], s = src[e];
            float w = ew[e];
            int r = d >> 8;
            myr[j] = r;
            myrec[j] = (u64)((unsigned)s | ((unsigned)(d & 255) << 17)) | ((u64)__float_as_uint(w) << 32);
            atomicAdd(&hist[r], 1);
        } else myr[j] = -1;
    }
    __syncthreads();

    // wave 0: exclusive scan of hist[512] -> loff
    if (tid < 64) {
        int sums[8], tot = 0;
#pragma unroll
        for (int q = 0; q < 8; q++) { sums[q] = hist[tid * 8 + q]; tot += sums[q]; }
        int scan = tot;
#pragma unroll
        for (int o = 1; o < 64; o <<= 1) {
            int v = __shfl_up(scan, o);
            if (tid >= o) scan += v;
        }
        int run = scan - tot;   // exclusive
#pragma unroll
        for (int q = 0; q < 8; q++) { loff[tid * 8 + q] = run; run += sums[q]; }
    }
    if (tid < 512) curL[tid] = 0;
    if (tid < R) {
        int hcnt = hist[tid];
        if (hcnt > 0) gbase[tid] = tid * CAPC + atomicAdd(&cursor[tid], hcnt);
    }
    __syncthreads();

    // place into LDS, bucket-sorted
#pragma unroll
    for (int j = 0; j < 6; j++) {
        if (myr[j] >= 0) {
            int p = atomicAdd(&curL[myr[j]], 1);
            recs[loff[myr[j]] + p] = myrec[j];
        }
    }
    __syncthreads();

    // flush: wave w handles buckets w, w+16, ... with coalesced runs
    int wave = tid >> 6, lane = tid & 63;
    for (int r = wave; r < R; r += 16) {
        int len = hist[r];
        if (!len) continue;
        int gb = gbase[r], lo = loff[r];
        int capEnd = (r + 1) * CAPC;
        for (int i = lane; i < len; i += 64)
            if (gb + i < capEnd) binned[(size_t)(gb + i)] = recs[lo + i];
    }
}

// Per-bucket: ONE global read stages records into LDS while building histogram +
// u64 fixed-point weighted degree (native ds_add_u64; f32 LDS atomic = CAS trap).
// After the scan, ticket-place from LDS directly to the sorted global position —
// scattered writes stay within this block's 43.5 KB bucket region (L2-resident,
// lines fully written before eviction -> no round-6-style write amplification).
__global__ void __launch_bounds__(1024) k_sort(const int* __restrict__ cursor,
                                               u64* __restrict__ binned,
                                               const float2* __restrict__ x2,
                                               float* __restrict__ dinv,
                                               __half2* __restrict__ xs2,
                                               int* __restrict__ off_g, int* __restrict__ len_g,
                                               int n) {
    __shared__ u64 srt[CAPC];        // 43.5 KB
    __shared__ int hist[256];
    __shared__ int noff[256];
    __shared__ int cur[256];
    __shared__ u64 degw64[256];
    __shared__ float dvS[256];

    int r = blockIdx.x, tid = threadIdx.x;
    if (tid < 256) { hist[tid] = 0; degw64[tid] = 0ULL; }
    __syncthreads();

    int cnt = min(cursor[r], CAPC);
    u64* B = binned + (size_t)r * CAPC;

    // pass A: stage to LDS + histogram + weighted degree (single global read)
    for (int i = tid; i < cnt; i += 1024) {
        u64 m = B[i];
        srt[i] = m;
        int dl = ((unsigned)m >> 17) & 255;
        atomicAdd(&hist[dl], 1);
        float w = __uint_as_float((unsigned)(m >> 32));
        atomicAdd(&degw64[dl], (u64)(w * 4294967296.0f));
    }
    __syncthreads();

    // wave 0: exclusive scan hist[256] -> noff
    if (tid < 64) {
        int s0 = hist[tid * 4], s1 = hist[tid * 4 + 1], s2 = hist[tid * 4 + 2], s3 = hist[tid * 4 + 3];
        int tot = s0 + s1 + s2 + s3;
        int scan = tot;
#pragma unroll
        for (int o = 1; o < 64; o <<= 1) {
            int v = __shfl_up(scan, o);
            if (tid >= o) scan += v;
        }
        int run = scan - tot;
        noff[tid * 4] = run; run += s0;
        noff[tid * 4 + 1] = run; run += s1;
        noff[tid * 4 + 2] = run; run += s2;
        noff[tid * 4 + 3] = run;
    }
    __syncthreads();

    if (tid < 256) {
        int node = r * 256 + tid;
        float deg = (float)degw64[tid] * 0x1p-32f;
        float dv = rsqrtf(1.0f + deg);
        if (node < n) {
            dinv[node] = dv;
            off_g[node] = r * CAPC + noff[tid];
            len_g[node] = hist[tid];
        }
        cur[tid] = noff[tid];
        dvS[tid] = dv;
    }
    __syncthreads();

    // pass B: ticket-place from LDS straight to sorted global slot
    for (int i = tid; i < cnt; i += 1024) {
        u64 m = srt[i];
        int dl = ((unsigned)m >> 17) & 255;
        int p = atomicAdd(&cur[dl], 1);
        B[p] = (u64)((unsigned)m & 0x1FFFF) | (m & 0xFFFFFFFF00000000ULL);
    }

    // xs build (independent stream; no sync needed with pass B)
    int nbase = r * 256;
    for (int i = tid; i < 256 * 32; i += 1024) {
        int nl = i >> 5, cp = i & 31;
        int node = nbase + nl;
        if (node < n) {
            float2 xv = x2[((size_t)node << 5) + cp];
            float dv = dvS[nl];
            xs2[((size_t)node << 5) + cp] = __floats2half2_rn(dv * xv.x, dv * xv.y);
        }
    }
}

// wave per node over CSR runs: agg = dd * (xs[d] + sum ew*xs[src]); ILP-16
// (exact round-0 structure: proven best across 3 restructure attempts).
// d_base: node offset so the launch can be split into two serial half-dispatches
// (instrumentation: exposes the second-hottest kernel in the profile top-5).
__global__ void __launch_bounds__(256) k_gather(const int* __restrict__ off_g, const int* __restrict__ len_g,
                                                const u64* __restrict__ csr, const float* __restrict__ dinv,
                                                const __half* __restrict__ xs,
                                                __half* __restrict__ aggh, int n, int d_base) {
    int lane = threadIdx.x & 63;
    int wid = __builtin_amdgcn_readfirstlane(threadIdx.x >> 6);
    int d = d_base + blockIdx.x * 4 + wid;
    if (d >= n) return;
    int o0 = off_g[d], L = len_g[d];
    float dd = dinv[d];
    float acc[16];
#pragma unroll
    for (int j = 0; j < 16; j++) acc[j] = 0.f;
    acc[0] = (float)xs[((size_t)d << 6) + lane];   // self term (weight 1 in scaled space)

    for (int base = 0; base < L; base += 64) {
        int c = min(64, L - base);
        u64 m = (lane < c) ? csr[(size_t)(o0 + base) + lane] : 0;
        int s_l = (unsigned)m & 0x1FFFF;
        float w_l = __uint_as_float((unsigned)(m >> 32));
        int k = 0;
        for (; k + 16 <= c; k += 16) {
            int ss[16]; float ww[16], xr[16];
#pragma unroll
            for (int j = 0; j < 16; j++) { ss[j] = rli(s_l, k + j); ww[j] = rlf(w_l, k + j); }
#pragma unroll
            for (int j = 0; j < 16; j++) xr[j] = (float)xs[((size_t)ss[j] << 6) + lane];
#pragma unroll
            for (int j = 0; j < 16; j++) acc[j] = fmaf(ww[j], xr[j], acc[j]);
        }
        for (; k + 4 <= c; k += 4) {
            int ss[4]; float ww[4], xr[4];
#pragma unroll
            for (int j = 0; j < 4; j++) { ss[j] = rli(s_l, k + j); ww[j] = rlf(w_l, k + j); }
#pragma unroll
            for (int j = 0; j < 4; j++) xr[j] = (float)xs[((size_t)ss[j] << 6) + lane];
#pragma unroll
            for (int j = 0; j < 4; j++) acc[j] = fmaf(ww[j], xr[j], acc[j]);
        }
        for (; k < c; k++) {
            int s0 = rli(s_l, k);
            float w0 = rlf(w_l, k);
            acc[0] = fmaf(w0, (float)xs[((size_t)s0 << 6) + lane], acc[0]);
        }
    }
    float s = ((acc[0] + acc[1]) + (acc[2] + acc[3])) + ((acc[4] + acc[5]) + (acc[6] + acc[7]))
            + ((acc[8] + acc[9]) + (acc[10] + acc[11])) + ((acc[12] + acc[13]) + (acc[14] + acc[15]));
    aggh[((size_t)d << 7) + lane] = (__half)(dd * s);
}

// MFMA gate kernel (body unchanged, known-good); grid = one 64-node group per block
__global__ void __launch_bounds__(256, 2) k_node(
        const __half* __restrict__ aggh,
        const __half* __restrict__ B1f_g, const __half* __restrict__ B2f_g,
        const float* __restrict__ bias_g, const float* __restrict__ Whead,
        const float* __restrict__ bhead,
        float* __restrict__ out_head, float* __restrict__ out_h, int n) {

    __shared__ __half B1s[24576];
    __shared__ __half B2s[4096];
    __shared__ float biasS[192];
    __shared__ float whS[64];
    __shared__ __half hrb[4][16 * 72];

    int tid = threadIdx.x;
    {
        const uint4* s1 = (const uint4*)B1f_g; uint4* d1 = (uint4*)B1s;
        for (int i = tid; i < 3072; i += 256) d1[i] = s1[i];
        const uint4* s2 = (const uint4*)B2f_g; uint4* d2 = (uint4*)B2s;
        for (int i = tid; i < 512; i += 256) d2[i] = s2[i];
        if (tid < 192) biasS[tid] = bias_g[tid];
        if (tid < 64) whS[tid] = Whead[tid];
    }
    __syncthreads();

    int lane = tid & 63;
    int wave = tid >> 6;
    int quad = lane >> 4;
    int l15 = lane & 15;

    float bz4[4], br4[4], bh4[4], wh4[4];
#pragma unroll
    for (int nt = 0; nt < 4; nt++) {
        bz4[nt] = biasS[nt * 16 + l15];
        br4[nt] = biasS[64 + nt * 16 + l15];
        bh4[nt] = biasS[128 + nt * 16 + l15];
        wh4[nt] = whS[nt * 16 + l15];
    }
    float bhv = bhead[0];
    __half* myhr = &hrb[wave][0];
    const half8* B1v = (const half8*)B1s;
    const half8* B2v = (const half8*)B2s;

    int mbase = blockIdx.x * 64 + wave * 16;
    if (mbase < n) {
        const half8* arow = (const half8*)(aggh + (((size_t)(mbase + l15)) << 7) + (quad << 3));
        half8 a0 = arow[0], a1 = arow[4], a2 = arow[8], a3 = arow[12];

        f32x4 acc[12];
#pragma unroll
        for (int nt = 0; nt < 12; nt++) acc[nt] = (f32x4){0.f, 0.f, 0.f, 0.f};

#pragma unroll
        for (int nt = 0; nt < 12; nt++) {
            acc[nt] = __builtin_amdgcn_mfma_f32_16x16x32_f16(a0, B1v[(0 * 12 + nt) * 64 + lane], acc[nt], 0, 0, 0);
            acc[nt] = __builtin_amdgcn_mfma_f32_16x16x32_f16(a1, B1v[(1 * 12 + nt) * 64 + lane], acc[nt], 0, 0, 0);
            acc[nt] = __builtin_amdgcn_mfma_f32_16x16x32_f16(a2, B1v[(2 * 12 + nt) * 64 + lane], acc[nt], 0, 0, 0);
            acc[nt] = __builtin_amdgcn_mfma_f32_16x16x32_f16(a3, B1v[(3 * 12 + nt) * 64 + lane], acc[nt], 0, 0, 0);
        }

        float hv[4][4];
#pragma unroll
        for (int nt = 0; nt < 4; nt++)
#pragma unroll
            for (int r = 0; r < 4; r++)
                hv[nt][r] = (float)aggh[(((size_t)(mbase + quad * 4 + r)) << 7) + 64 + nt * 16 + l15];

        float Z[4][4];
#pragma unroll
        for (int nt = 0; nt < 4; nt++)
#pragma unroll
            for (int r = 0; r < 4; r++) {
                Z[nt][r] = sigm(acc[nt][r] + bz4[nt]);
                float R = sigm(acc[4 + nt][r] + br4[nt]);
                myhr[(quad * 4 + r) * 72 + nt * 16 + l15] = (__half)(hv[nt][r] * R);
            }
        __builtin_amdgcn_s_waitcnt(0);

        half8 a2f0 = *(const half8*)(myhr + l15 * 72 + quad * 8);
        half8 a2f1 = *(const half8*)(myhr + l15 * 72 + 32 + quad * 8);

#pragma unroll
        for (int nt = 0; nt < 4; nt++) {
            acc[8 + nt] = __builtin_amdgcn_mfma_f32_16x16x32_f16(a2f0, B2v[(0 * 4 + nt) * 64 + lane], acc[8 + nt], 0, 0, 0);
            acc[8 + nt] = __builtin_amdgcn_mfma_f32_16x16x32_f16(a2f1, B2v[(1 * 4 + nt) * 64 + lane], acc[8 + nt], 0, 0, 0);
        }

        float pr0 = 0.f, pr1 = 0.f, pr2 = 0.f, pr3 = 0.f;
#pragma unroll
        for (int nt = 0; nt < 4; nt++) {
#pragma unroll
            for (int r = 0; r < 4; r++) {
                float Ht = tanhfast(acc[8 + nt][r] + bh4[nt]);
                float z = Z[nt][r];
                float hn = z * hv[nt][r] + (1.f - z) * Ht;
                out_h[((size_t)(mbase + quad * 4 + r)) * 64 + nt * 16 + l15] = hn;
                float rv = fmaxf(hn, 0.f) * wh4[nt];
                if (r == 0) pr0 += rv; else if (r == 1) pr1 += rv; else if (r == 2) pr2 += rv; else pr3 += rv;
            }
        }
#pragma unroll
        for (int o = 1; o < 16; o <<= 1) {
            pr0 += __shfl_xor(pr0, o);
            pr1 += __shfl_xor(pr1, o);
            pr2 += __shfl_xor(pr2, o);
            pr3 += __shfl_xor(pr3, o);
        }
        if (l15 == 0) {
            out_head[mbase + quad * 4 + 0] = pr0 + bhv;
            out_head[mbase + quad * 4 + 1] = pr1 + bhv;
            out_head[mbase + quad * 4 + 2] = pr2 + bhv;
            out_head[mbase + quad * 4 + 3] = pr3 + bhv;
        }
    }
}

extern "C" void kernel_launch(void* const* d_in, const int* in_sizes, int n_in,
                              void* d_out, int out_size, void* d_ws, size_t ws_size,
                              hipStream_t stream) {
    const float* x     = (const float*)d_in[0];
    const int*   src   = (const int*)d_in[1];
    const int*   dst   = (const int*)d_in[2];
    const float* ew    = (const float*)d_in[3];
    const float* h     = (const float*)d_in[4];
    const float* Wcz   = (const float*)d_in[5];
    const float* bcz   = (const float*)d_in[6];
    const float* Wcr   = (const float*)d_in[7];
    const float* bcr   = (const float*)d_in[8];
    const float* Wch   = (const float*)d_in[9];
    const float* bch   = (const float*)d_in[10];
    const float* Wlz   = (const float*)d_in[11];
    const float* blz   = (const float*)d_in[12];
    const float* Wlr   = (const float*)d_in[13];
    const float* blr   = (const float*)d_in[14];
    const float* Wlh   = (const float*)d_in[15];
    const float* blh   = (const float*)d_in[16];
    const float* Whead = (const float*)d_in[17];
    const float* bhead = (const float*)d_in[18];

    int E = in_sizes[1];
    int n = in_sizes[4] / 64;                 // 100000 nodes
    int R = (n + 255) >> 8;                   // 391 buckets of 256 nodes

    // workspace layout
    __half* aggh = (__half*)d_ws;                        // n*128 fp16: [agg | h]
    __half* xs   = aggh + (size_t)n * 128;               // n*64 fp16 (dinv-scaled x)
    u64*   binned = (u64*)(xs + (size_t)n * 64);         // R*CAPC u64
    float* dinv  = (float*)(binned + (size_t)R * CAPC);  // n f32
    int*   off_g = (int*)(dinv + n);                     // n
    int*   len_g = off_g + n;                            // n
    int*   cursor = len_g + n;                           // 1024
    __half* B1f  = (__half*)(cursor + 1024);             // 24576 fp16
    __half* B2f  = B1f + 24576;                          // 4096 fp16
    float* bias  = (float*)(B2f + 4096);                 // 192 f32

    float* out_head = (float*)d_out;          // [n]
    float* out_h    = out_head + n;           // [n*64]

    int hq = n * 16;                          // float4 groups of h
    int nbB = (E + EPB - 1) / EPB;
    int gridPre = 113 + (hq + 255) / 256;

    k_pre<<<gridPre, 256, 0, stream>>>(Wcz, bcz, Wcr, bcr, Wch, bch,
                                       Wlz, blz, Wlr, blr, Wlh, blh,
                                       (const float4*)h, aggh, B1f, B2f, bias, cursor, hq);
    k_bin<<<nbB, 1024, 0, stream>>>(src, dst, ew, cursor, binned, E, R);
    k_sort<<<R, 1024, 0, stream>>>(cursor, binned, (const float2*)x, dinv,
                                   (__half2*)xs, off_g, len_g, n);
    int nbG = (n + 3) / 4;
    int nbG1 = nbG / 2;
    k_gather<<<nbG1, 256, 0, stream>>>(off_g, len_g, binned, dinv, xs, aggh, n, 0);
    k_gather<<<nbG - nbG1, 256, 0, stream>>>(off_g, len_g, binned, dinv, xs, aggh, n, nbG1 * 4);
    k_node<<<(n + 63) / 64, 256, 0, stream>>>(aggh, B1f, B2f, bias, Whead, bhead,
                                              out_head, out_h, n);
}

// Round 8
// 243.465 us; speedup vs baseline: 1.7002x; 1.0276x over previous
//
#include <hip/hip_runtime.h>
#include <hip/hip_fp16.h>
#include <stdint.h>

typedef unsigned long long u64;
typedef _Float16 half8 __attribute__((ext_vector_type(8)));
typedef float f32x4 __attribute__((ext_vector_type(4)));

#define EPB 6144      // edges staged per k_bin block
#define CAPC 5440     // bucket capacity (mean 4096 + huge margin)

__device__ __forceinline__ float sigm(float x) { return 1.0f / (1.0f + __expf(-x)); }
__device__ __forceinline__ float tanhfast(float x) { return 1.0f - 2.0f / (__expf(2.0f * x) + 1.0f); }
__device__ __forceinline__ int rli(int v, int k) { return __builtin_amdgcn_readlane(v, k); }
__device__ __forceinline__ float rlf(float v, int k) {
    return __int_as_float(__builtin_amdgcn_readlane(__float_as_int(v), k));
}

// Merged: fragment-packed weight build (blocks 0..112) + h->fp16 (blocks 113..) + cursor zero.
__global__ void k_pre(const float* __restrict__ Wcz, const float* __restrict__ bcz,
                      const float* __restrict__ Wcr, const float* __restrict__ bcr,
                      const float* __restrict__ Wch, const float* __restrict__ bch,
                      const float* __restrict__ Wlz, const float* __restrict__ blz,
                      const float* __restrict__ Wlr, const float* __restrict__ blr,
                      const float* __restrict__ Wlh, const float* __restrict__ blh,
                      const float4* __restrict__ h4, __half* __restrict__ aggh,
                      __half* __restrict__ B1f, __half* __restrict__ B2f,
                      float* __restrict__ bias, int* __restrict__ cursor, int hq) {
    int bid = blockIdx.x;
    if (bid < 113) {
        int tid = bid * 256 + threadIdx.x;
        if (tid < 1024) cursor[tid] = 0;
        if (tid < 24576) {
            int k = tid / 192, nc = tid % 192;
            int g = nc >> 6, j = nc & 63;
            const float* Wc = (g == 0) ? Wcz : (g == 1) ? Wcr : Wch;
            const float* Wl = (g == 0) ? Wlz : (g == 1) ? Wlr : Wlh;
            float v;
            if (k < 64) {
                float acc = 0.f;
                for (int m = 0; m < 64; m++) acc += Wc[k * 64 + m] * Wl[m * 64 + j];
                v = acc;
            } else {
                v = (g < 2) ? Wl[k * 64 + j] : 0.f;
            }
            int kt = k >> 5, nt = nc >> 4;
            int lane = (((k >> 3) & 3) << 4) | (nc & 15);
            B1f[(((kt * 12 + nt) * 64 + lane) << 3) + (k & 7)] = (__half)v;
        } else if (tid < 24576 + 4096) {
            int t = tid - 24576;
            int k = t >> 6, nc = t & 63;
            float v = Wlh[(64 + k) * 64 + nc];
            int kt = k >> 5, nt = nc >> 4;
            int lane = (((k >> 3) & 3) << 4) | (nc & 15);
            B2f[(((kt * 4 + nt) * 64 + lane) << 3) + (k & 7)] = (__half)v;
        } else if (tid < 24576 + 4096 + 192) {
            int t = tid - 24576 - 4096;
            int g = t >> 6, j = t & 63;
            const float* bc = (g == 0) ? bcz : (g == 1) ? bcr : bch;
            const float* Wl = (g == 0) ? Wlz : (g == 1) ? Wlr : Wlh;
            const float* bl = (g == 0) ? blz : (g == 1) ? blr : blh;
            float acc = bl[j];
            for (int m = 0; m < 64; m++) acc += bc[m] * Wl[m * 64 + j];
            bias[t] = acc;
        }
    } else {
        int i = (bid - 113) * 256 + threadIdx.x;
        if (i < hq) {
            float4 hv = h4[i];
            int elem = i * 4;
            int node = elem >> 6, c = elem & 63;
            __half2* ho = (__half2*)(aggh + (((size_t)node) << 7) + 64 + c);
            ho[0] = __floats2half2_rn(hv.x, hv.y);
            ho[1] = __floats2half2_rn(hv.z, hv.w);
        }
    }
}

// One-pass LDS-staged counting sort of edges into 256-node dst-buckets.
// rec u64: [63:32]=ew bits, [24:17]=dst&255, [16:0]=src
__global__ void __launch_bounds__(1024) k_bin(const int* __restrict__ src, const int* __restrict__ dst,
                                              const float* __restrict__ ew,
                                              int* __restrict__ cursor, u64* __restrict__ binned,
                                              int E, int R) {
    __shared__ u64 recs[EPB];        // 48 KB
    __shared__ int hist[512];
    __shared__ int loff[512];
    __shared__ int curL[512];
    __shared__ int gbase[512];

    int tid = threadIdx.x;
    if (tid < 512) hist[tid] = 0;
    __syncthreads();

    int base = blockIdx.x * EPB;
    int cntE = min(EPB, E - base);

    u64 myrec[6];
    int myr[6];
#pragma unroll
    for (int j = 0; j < 6; j++) {
        int idx = tid + j * 1024;
        if (idx < cntE) {
            int e = base + idx;
            int d = dst[e], s = src[e];
            float w = ew[e];
            int r = d >> 8;
            myr[j] = r;
            myrec[j] = (u64)((unsigned)s | ((unsigned)(d & 255) << 17)) | ((u64)__float_as_uint(w) << 32);
            atomicAdd(&hist[r], 1);
        } else myr[j] = -1;
    }
    __syncthreads();

    // wave 0: exclusive scan of hist[512] -> loff
    if (tid < 64) {
        int sums[8], tot = 0;
#pragma unroll
        for (int q = 0; q < 8; q++) { sums[q] = hist[tid * 8 + q]; tot += sums[q]; }
        int scan = tot;
#pragma unroll
        for (int o = 1; o < 64; o <<= 1) {
            int v = __shfl_up(scan, o);
            if (tid >= o) scan += v;
        }
        int run = scan - tot;   // exclusive
#pragma unroll
        for (int q = 0; q < 8; q++) { loff[tid * 8 + q] = run; run += sums[q]; }
    }
    if (tid < 512) curL[tid] = 0;
    if (tid < R) {
        int hcnt = hist[tid];
        if (hcnt > 0) gbase[tid] = tid * CAPC + atomicAdd(&cursor[tid], hcnt);
    }
    __syncthreads();

    // place into LDS, bucket-sorted
#pragma unroll
    for (int j = 0; j < 6; j++) {
        if (myr[j] >= 0) {
            int p = atomicAdd(&curL[myr[j]], 1);
            recs[loff[myr[j]] + p] = myrec[j];
        }
    }
    __syncthreads();

    // flush: wave w handles buckets w, w+16, ... with coalesced runs
    int wave = tid >> 6, lane = tid & 63;
    for (int r = wave; r < R; r += 16) {
        int len = hist[r];
        if (!len) continue;
        int gb = gbase[r], lo = loff[r];
        int capEnd = (r + 1) * CAPC;
        for (int i = lane; i < len; i += 64)
            if (gb + i < capEnd) binned[(size_t)(gb + i)] = recs[lo + i];
    }
}

// Per-bucket: histogram+degree -> scan -> dinv/off/len; ticket-sort to CSR in place;
// also builds xs[i] = dinv[i] * x[i] in fp16 for this bucket's 256 nodes.
// Degree accumulation uses u64 FIXED-POINT (w * 2^32) with NATIVE ds_add_u64 —
// f32 LDS atomicAdd compiles to a CAS retry loop on gfx950 (round-2 lesson).
// (Round-4 form: L2-hot re-read + LDS ticket + coalesced flush — proven best;
// round-7's LDS->scattered-global pass B was ~11 us slower.)
__global__ void __launch_bounds__(1024) k_sort(const int* __restrict__ cursor,
                                               u64* __restrict__ binned,
                                               const float2* __restrict__ x2,
                                               float* __restrict__ dinv,
                                               __half2* __restrict__ xs2,
                                               int* __restrict__ off_g, int* __restrict__ len_g,
                                               int n) {
    __shared__ u64 srt[CAPC];        // 43.5 KB
    __shared__ int hist[256];
    __shared__ int noff[256];
    __shared__ int cur[256];
    __shared__ u64 degw64[256];
    __shared__ float dvS[256];

    int r = blockIdx.x, tid = threadIdx.x;
    if (tid < 256) { hist[tid] = 0; degw64[tid] = 0ULL; }
    __syncthreads();

    int cnt = min(cursor[r], CAPC);
    u64* B = binned + (size_t)r * CAPC;

    // pass A: histogram + weighted degree (u64 fixed point, native atomic)
    for (int i = tid; i < cnt; i += 1024) {
        u64 m = B[i];
        int dl = ((unsigned)m >> 17) & 255;
        atomicAdd(&hist[dl], 1);
        float w = __uint_as_float((unsigned)(m >> 32));
        atomicAdd(&degw64[dl], (u64)(w * 4294967296.0f));
    }
    __syncthreads();

    // wave 0: exclusive scan hist[256] -> noff
    if (tid < 64) {
        int s0 = hist[tid * 4], s1 = hist[tid * 4 + 1], s2 = hist[tid * 4 + 2], s3 = hist[tid * 4 + 3];
        int tot = s0 + s1 + s2 + s3;
        int scan = tot;
#pragma unroll
        for (int o = 1; o < 64; o <<= 1) {
            int v = __shfl_up(scan, o);
            if (tid >= o) scan += v;
        }
        int run = scan - tot;
        noff[tid * 4] = run; run += s0;
        noff[tid * 4 + 1] = run; run += s1;
        noff[tid * 4 + 2] = run; run += s2;
        noff[tid * 4 + 3] = run;
    }
    __syncthreads();

    if (tid < 256) {
        int node = r * 256 + tid;
        float deg = (float)degw64[tid] * 0x1p-32f;
        float dv = rsqrtf(1.0f + deg);
        if (node < n) {
            dinv[node] = dv;
            off_g[node] = r * CAPC + noff[tid];
            len_g[node] = hist[tid];
        }
        cur[tid] = noff[tid];
        dvS[tid] = dv;
    }
    __syncthreads();

    // pass B: ticket-place into sorted LDS order (global L2-hot re-read -> LDS)
    for (int i = tid; i < cnt; i += 1024) {
        u64 m = B[i];
        int dl = ((unsigned)m >> 17) & 255;
        int p = atomicAdd(&cur[dl], 1);
        srt[p] = (u64)((unsigned)m & 0x1FFFF) | (m & 0xFFFFFFFF00000000ULL);
    }
    __syncthreads();

    // coalesced in-place flush + xs build (independent streams)
    for (int i = tid; i < cnt; i += 1024) B[i] = srt[i];
    int nbase = r * 256;
    for (int i = tid; i < 256 * 32; i += 1024) {
        int nl = i >> 5, cp = i & 31;
        int node = nbase + nl;
        if (node < n) {
            float2 xv = x2[((size_t)node << 5) + cp];
            float dv = dvS[nl];
            xs2[((size_t)node << 5) + cp] = __floats2half2_rn(dv * xv.x, dv * xv.y);
        }
    }
}

// wave per node over CSR runs: agg = dd * (xs[d] + sum ew*xs[src]); ILP-16
// (exact round-0 structure: proven best across 4 restructure attempts).
// CSR loads are NON-TEMPORAL: the 12.8 MB record stream is read exactly once,
// so evict-first tagging preserves L2 residency for the randomly re-read xs.
__global__ void __launch_bounds__(256) k_gather(const int* __restrict__ off_g, const int* __restrict__ len_g,
                                                const u64* __restrict__ csr, const float* __restrict__ dinv,
                                                const __half* __restrict__ xs,
                                                __half* __restrict__ aggh, int n) {
    int lane = threadIdx.x & 63;
    int wid = __builtin_amdgcn_readfirstlane(threadIdx.x >> 6);
    int d = blockIdx.x * 4 + wid;
    if (d >= n) return;
    int o0 = off_g[d], L = len_g[d];
    float dd = dinv[d];
    float acc[16];
#pragma unroll
    for (int j = 0; j < 16; j++) acc[j] = 0.f;
    acc[0] = (float)xs[((size_t)d << 6) + lane];   // self term (weight 1 in scaled space)

    for (int base = 0; base < L; base += 64) {
        int c = min(64, L - base);
        u64 m = (lane < c) ? __builtin_nontemporal_load(&csr[(size_t)(o0 + base) + lane]) : 0;
        int s_l = (unsigned)m & 0x1FFFF;
        float w_l = __uint_as_float((unsigned)(m >> 32));
        int k = 0;
        for (; k + 16 <= c; k += 16) {
            int ss[16]; float ww[16], xr[16];
#pragma unroll
            for (int j = 0; j < 16; j++) { ss[j] = rli(s_l, k + j); ww[j] = rlf(w_l, k + j); }
#pragma unroll
            for (int j = 0; j < 16; j++) xr[j] = (float)xs[((size_t)ss[j] << 6) + lane];
#pragma unroll
            for (int j = 0; j < 16; j++) acc[j] = fmaf(ww[j], xr[j], acc[j]);
        }
        for (; k + 4 <= c; k += 4) {
            int ss[4]; float ww[4], xr[4];
#pragma unroll
            for (int j = 0; j < 4; j++) { ss[j] = rli(s_l, k + j); ww[j] = rlf(w_l, k + j); }
#pragma unroll
            for (int j = 0; j < 4; j++) xr[j] = (float)xs[((size_t)ss[j] << 6) + lane];
#pragma unroll
            for (int j = 0; j < 4; j++) acc[j] = fmaf(ww[j], xr[j], acc[j]);
        }
        for (; k < c; k++) {
            int s0 = rli(s_l, k);
            float w0 = rlf(w_l, k);
            acc[0] = fmaf(w0, (float)xs[((size_t)s0 << 6) + lane], acc[0]);
        }
    }
    float s = ((acc[0] + acc[1]) + (acc[2] + acc[3])) + ((acc[4] + acc[5]) + (acc[6] + acc[7]))
            + ((acc[8] + acc[9]) + (acc[10] + acc[11])) + ((acc[12] + acc[13]) + (acc[14] + acc[15]));
    aggh[((size_t)d << 7) + lane] = (__half)(dd * s);
}

// MFMA gate kernel (body unchanged, known-good); grid = one 64-node group per block
__global__ void __launch_bounds__(256, 2) k_node(
        const __half* __restrict__ aggh,
        const __half* __restrict__ B1f_g, const __half* __restrict__ B2f_g,
        const float* __restrict__ bias_g, const float* __restrict__ Whead,
        const float* __restrict__ bhead,
        float* __restrict__ out_head, float* __restrict__ out_h, int n) {

    __shared__ __half B1s[24576];
    __shared__ __half B2s[4096];
    __shared__ float biasS[192];
    __shared__ float whS[64];
    __shared__ __half hrb[4][16 * 72];

    int tid = threadIdx.x;
    {
        const uint4* s1 = (const uint4*)B1f_g; uint4* d1 = (uint4*)B1s;
        for (int i = tid; i < 3072; i += 256) d1[i] = s1[i];
        const uint4* s2 = (const uint4*)B2f_g; uint4* d2 = (uint4*)B2s;
        for (int i = tid; i < 512; i += 256) d2[i] = s2[i];
        if (tid < 192) biasS[tid] = bias_g[tid];
        if (tid < 64) whS[tid] = Whead[tid];
    }
    __syncthreads();

    int lane = tid & 63;
    int wave = tid >> 6;
    int quad = lane >> 4;
    int l15 = lane & 15;

    float bz4[4], br4[4], bh4[4], wh4[4];
#pragma unroll
    for (int nt = 0; nt < 4; nt++) {
        bz4[nt] = biasS[nt * 16 + l15];
        br4[nt] = biasS[64 + nt * 16 + l15];
        bh4[nt] = biasS[128 + nt * 16 + l15];
        wh4[nt] = whS[nt * 16 + l15];
    }
    float bhv = bhead[0];
    __half* myhr = &hrb[wave][0];
    const half8* B1v = (const half8*)B1s;
    const half8* B2v = (const half8*)B2s;

    int mbase = blockIdx.x * 64 + wave * 16;
    if (mbase < n) {
        const half8* arow = (const half8*)(aggh + (((size_t)(mbase + l15)) << 7) + (quad << 3));
        half8 a0 = arow[0], a1 = arow[4], a2 = arow[8], a3 = arow[12];

        f32x4 acc[12];
#pragma unroll
        for (int nt = 0; nt < 12; nt++) acc[nt] = (f32x4){0.f, 0.f, 0.f, 0.f};

#pragma unroll
        for (int nt = 0; nt < 12; nt++) {
            acc[nt] = __builtin_amdgcn_mfma_f32_16x16x32_f16(a0, B1v[(0 * 12 + nt) * 64 + lane], acc[nt], 0, 0, 0);
            acc[nt] = __builtin_amdgcn_mfma_f32_16x16x32_f16(a1, B1v[(1 * 12 + nt) * 64 + lane], acc[nt], 0, 0, 0);
            acc[nt] = __builtin_amdgcn_mfma_f32_16x16x32_f16(a2, B1v[(2 * 12 + nt) * 64 + lane], acc[nt], 0, 0, 0);
            acc[nt] = __builtin_amdgcn_mfma_f32_16x16x32_f16(a3, B1v[(3 * 12 + nt) * 64 + lane], acc[nt], 0, 0, 0);
        }

        float hv[4][4];
#pragma unroll
        for (int nt = 0; nt < 4; nt++)
#pragma unroll
            for (int r = 0; r < 4; r++)
                hv[nt][r] = (float)aggh[(((size_t)(mbase + quad * 4 + r)) << 7) + 64 + nt * 16 + l15];

        float Z[4][4];
#pragma unroll
        for (int nt = 0; nt < 4; nt++)
#pragma unroll
            for (int r = 0; r < 4; r++) {
                Z[nt][r] = sigm(acc[nt][r] + bz4[nt]);
                float R = sigm(acc[4 + nt][r] + br4[nt]);
                myhr[(quad * 4 + r) * 72 + nt * 16 + l15] = (__half)(hv[nt][r] * R);
            }
        __builtin_amdgcn_s_waitcnt(0);

        half8 a2f0 = *(const half8*)(myhr + l15 * 72 + quad * 8);
        half8 a2f1 = *(const half8*)(myhr + l15 * 72 + 32 + quad * 8);

#pragma unroll
        for (int nt = 0; nt < 4; nt++) {
            acc[8 + nt] = __builtin_amdgcn_mfma_f32_16x16x32_f16(a2f0, B2v[(0 * 4 + nt) * 64 + lane], acc[8 + nt], 0, 0, 0);
            acc[8 + nt] = __builtin_amdgcn_mfma_f32_16x16x32_f16(a2f1, B2v[(1 * 4 + nt) * 64 + lane], acc[8 + nt], 0, 0, 0);
        }

        float pr0 = 0.f, pr1 = 0.f, pr2 = 0.f, pr3 = 0.f;
#pragma unroll
        for (int nt = 0; nt < 4; nt++) {
#pragma unroll
            for (int r = 0; r < 4; r++) {
                float Ht = tanhfast(acc[8 + nt][r] + bh4[nt]);
                float z = Z[nt][r];
                float hn = z * hv[nt][r] + (1.f - z) * Ht;
                out_h[((size_t)(mbase + quad * 4 + r)) * 64 + nt * 16 + l15] = hn;
                float rv = fmaxf(hn, 0.f) * wh4[nt];
                if (r == 0) pr0 += rv; else if (r == 1) pr1 += rv; else if (r == 2) pr2 += rv; else pr3 += rv;
            }
        }
#pragma unroll
        for (int o = 1; o < 16; o <<= 1) {
            pr0 += __shfl_xor(pr0, o);
            pr1 += __shfl_xor(pr1, o);
            pr2 += __shfl_xor(pr2, o);
            pr3 += __shfl_xor(pr3, o);
        }
        if (l15 == 0) {
            out_head[mbase + quad * 4 + 0] = pr0 + bhv;
            out_head[mbase + quad * 4 + 1] = pr1 + bhv;
            out_head[mbase + quad * 4 + 2] = pr2 + bhv;
            out_head[mbase + quad * 4 + 3] = pr3 + bhv;
        }
    }
}

extern "C" void kernel_launch(void* const* d_in, const int* in_sizes, int n_in,
                              void* d_out, int out_size, void* d_ws, size_t ws_size,
                              hipStream_t stream) {
    const float* x     = (const float*)d_in[0];
    const int*   src   = (const int*)d_in[1];
    const int*   dst   = (const int*)d_in[2];
    const float* ew    = (const float*)d_in[3];
    const float* h     = (const float*)d_in[4];
    const float* Wcz   = (const float*)d_in[5];
    const float* bcz   = (const float*)d_in[6];
    const float* Wcr   = (const float*)d_in[7];
    const float* bcr   = (const float*)d_in[8];
    const float* Wch   = (const float*)d_in[9];
    const float* bch   = (const float*)d_in[10];
    const float* Wlz   = (const float*)d_in[11];
    const float* blz   = (const float*)d_in[12];
    const float* Wlr   = (const float*)d_in[13];
    const float* blr   = (const float*)d_in[14];
    const float* Wlh   = (const float*)d_in[15];
    const float* blh   = (const float*)d_in[16];
    const float* Whead = (const float*)d_in[17];
    const float* bhead = (const float*)d_in[18];

    int E = in_sizes[1];
    int n = in_sizes[4] / 64;                 // 100000 nodes
    int R = (n + 255) >> 8;                   // 391 buckets of 256 nodes

    // workspace layout
    __half* aggh = (__half*)d_ws;                        // n*128 fp16: [agg | h]
    __half* xs   = aggh + (size_t)n * 128;               // n*64 fp16 (dinv-scaled x)
    u64*   binned = (u64*)(xs + (size_t)n * 64);         // R*CAPC u64
    float* dinv  = (float*)(binned + (size_t)R * CAPC);  // n f32
    int*   off_g = (int*)(dinv + n);                     // n
    int*   len_g = off_g + n;                            // n
    int*   cursor = len_g + n;                           // 1024
    __half* B1f  = (__half*)(cursor + 1024);             // 24576 fp16
    __half* B2f  = B1f + 24576;                          // 4096 fp16
    float* bias  = (float*)(B2f + 4096);                 // 192 f32

    float* out_head = (float*)d_out;          // [n]
    float* out_h    = out_head + n;           // [n*64]

    int hq = n * 16;                          // float4 groups of h
    int nbB = (E + EPB - 1) / EPB;
    int gridPre = 113 + (hq + 255) / 256;

    k_pre<<<gridPre, 256, 0, stream>>>(Wcz, bcz, Wcr, bcr, Wch, bch,
                                       Wlz, blz, Wlr, blr, Wlh, blh,
                                       (const float4*)h, aggh, B1f, B2f, bias, cursor, hq);
    k_bin<<<nbB, 1024, 0, stream>>>(src, dst, ew, cursor, binned, E, R);
    k_sort<<<R, 1024, 0, stream>>>(cursor, binned, (const float2*)x, dinv,
                                   (__half2*)xs, off_g, len_g, n);
    k_gather<<<(n + 3) / 4, 256, 0, stream>>>(off_g, len_g, binned, dinv, xs, aggh, n);
    k_node<<<(n + 63) / 64, 256, 0, stream>>>(aggh, B1f, B2f, bias, Whead, bhead,
                                              out_head, out_h, n);
}

// Round 9
// 238.796 us; speedup vs baseline: 1.7334x; 1.0196x over previous
//
#include <hip/hip_runtime.h>
#include <hip/hip_fp16.h>
#include <stdint.h>

typedef unsigned long long u64;
typedef _Float16 half8 __attribute__((ext_vector_type(8)));
typedef float f32x4 __attribute__((ext_vector_type(4)));

#define EPB 6144      // edges staged per k_bin block
#define CAPC 5440     // bucket capacity (mean 4096 + huge margin)

__device__ __forceinline__ float sigm(float x) { return 1.0f / (1.0f + __expf(-x)); }
__device__ __forceinline__ float tanhfast(float x) { return 1.0f - 2.0f / (__expf(2.0f * x) + 1.0f); }
__device__ __forceinline__ int rli(int v, int k) { return __builtin_amdgcn_readlane(v, k); }
__device__ __forceinline__ float rlf(float v, int k) {
    return __int_as_float(__builtin_amdgcn_readlane(__float_as_int(v), k));
}

// Merged: fragment-packed weight build (blocks 0..112) + h->fp16 (blocks 113..) + cursor zero.
__global__ void k_pre(const float* __restrict__ Wcz, const float* __restrict__ bcz,
                      const float* __restrict__ Wcr, const float* __restrict__ bcr,
                      const float* __restrict__ Wch, const float* __restrict__ bch,
                      const float* __restrict__ Wlz, const float* __restrict__ blz,
                      const float* __restrict__ Wlr, const float* __restrict__ blr,
                      const float* __restrict__ Wlh, const float* __restrict__ blh,
                      const float4* __restrict__ h4, __half* __restrict__ aggh,
                      __half* __restrict__ B1f, __half* __restrict__ B2f,
                      float* __restrict__ bias, int* __restrict__ cursor, int hq) {
    int bid = blockIdx.x;
    if (bid < 113) {
        int tid = bid * 256 + threadIdx.x;
        if (tid < 1024) cursor[tid] = 0;
        if (tid < 24576) {
            int k = tid / 192, nc = tid % 192;
            int g = nc >> 6, j = nc & 63;
            const float* Wc = (g == 0) ? Wcz : (g == 1) ? Wcr : Wch;
            const float* Wl = (g == 0) ? Wlz : (g == 1) ? Wlr : Wlh;
            float v;
            if (k < 64) {
                float acc = 0.f;
                for (int m = 0; m < 64; m++) acc += Wc[k * 64 + m] * Wl[m * 64 + j];
                v = acc;
            } else {
                v = (g < 2) ? Wl[k * 64 + j] : 0.f;
            }
            int kt = k >> 5, nt = nc >> 4;
            int lane = (((k >> 3) & 3) << 4) | (nc & 15);
            B1f[(((kt * 12 + nt) * 64 + lane) << 3) + (k & 7)] = (__half)v;
        } else if (tid < 24576 + 4096) {
            int t = tid - 24576;
            int k = t >> 6, nc = t & 63;
            float v = Wlh[(64 + k) * 64 + nc];
            int kt = k >> 5, nt = nc >> 4;
            int lane = (((k >> 3) & 3) << 4) | (nc & 15);
            B2f[(((kt * 4 + nt) * 64 + lane) << 3) + (k & 7)] = (__half)v;
        } else if (tid < 24576 + 4096 + 192) {
            int t = tid - 24576 - 4096;
            int g = t >> 6, j = t & 63;
            const float* bc = (g == 0) ? bcz : (g == 1) ? bcr : bch;
            const float* Wl = (g == 0) ? Wlz : (g == 1) ? Wlr : Wlh;
            const float* bl = (g == 0) ? blz : (g == 1) ? blr : blh;
            float acc = bl[j];
            for (int m = 0; m < 64; m++) acc += bc[m] * Wl[m * 64 + j];
            bias[t] = acc;
        }
    } else {
        int i = (bid - 113) * 256 + threadIdx.x;
        if (i < hq) {
            float4 hv = h4[i];
            int elem = i * 4;
            int node = elem >> 6, c = elem & 63;
            __half2* ho = (__half2*)(aggh + (((size_t)node) << 7) + 64 + c);
            ho[0] = __floats2half2_rn(hv.x, hv.y);
            ho[1] = __floats2half2_rn(hv.z, hv.w);
        }
    }
}

// One-pass LDS-staged counting sort of edges into 256-node dst-buckets.
// rec u64: [63:32]=ew bits, [24:17]=dst&255, [16:0]=src
__global__ void __launch_bounds__(1024) k_bin(const int* __restrict__ src, const int* __restrict__ dst,
                                              const float* __restrict__ ew,
                                              int* __restrict__ cursor, u64* __restrict__ binned,
                                              int E, int R) {
    __shared__ u64 recs[EPB];        // 48 KB
    __shared__ int hist[512];
    __shared__ int loff[512];
    __shared__ int curL[512];
    __shared__ int gbase[512];

    int tid = threadIdx.x;
    if (tid < 512) hist[tid] = 0;
    __syncthreads();

    int base = blockIdx.x * EPB;
    int cntE = min(EPB, E - base);

    u64 myrec[6];
    int myr[6];
#pragma unroll
    for (int j = 0; j < 6; j++) {
        int idx = tid + j * 1024;
        if (idx < cntE) {
            int e = base + idx;
            int d = dst[e], s = src[e];
            float w = ew[e];
            int r = d >> 8;
            myr[j] = r;
            myrec[j] = (u64)((unsigned)s | ((unsigned)(d & 255) << 17)) | ((u64)__float_as_uint(w) << 32);
            atomicAdd(&hist[r], 1);
        } else myr[j] = -1;
    }
    __syncthreads();

    // wave 0: exclusive scan of hist[512] -> loff
    if (tid < 64) {
        int sums[8], tot = 0;
#pragma unroll
        for (int q = 0; q < 8; q++) { sums[q] = hist[tid * 8 + q]; tot += sums[q]; }
        int scan = tot;
#pragma unroll
        for (int o = 1; o < 64; o <<= 1) {
            int v = __shfl_up(scan, o);
            if (tid >= o) scan += v;
        }
        int run = scan - tot;   // exclusive
#pragma unroll
        for (int q = 0; q < 8; q++) { loff[tid * 8 + q] = run; run += sums[q]; }
    }
    if (tid < 512) curL[tid] = 0;
    if (tid < R) {
        int hcnt = hist[tid];
        if (hcnt > 0) gbase[tid] = tid * CAPC + atomicAdd(&cursor[tid], hcnt);
    }
    __syncthreads();

    // place into LDS, bucket-sorted
#pragma unroll
    for (int j = 0; j < 6; j++) {
        if (myr[j] >= 0) {
            int p = atomicAdd(&curL[myr[j]], 1);
            recs[loff[myr[j]] + p] = myrec[j];
        }
    }
    __syncthreads();

    // flush: wave w handles buckets w, w+16, ... with coalesced runs
    int wave = tid >> 6, lane = tid & 63;
    for (int r = wave; r < R; r += 16) {
        int len = hist[r];
        if (!len) continue;
        int gb = gbase[r], lo = loff[r];
        int capEnd = (r + 1) * CAPC;
        for (int i = lane; i < len; i += 64)
            if (gb + i < capEnd) binned[(size_t)(gb + i)] = recs[lo + i];
    }
}

// Per-bucket: histogram+degree -> scan -> dinv/off/len; ticket-sort to CSR in place;
// also builds xs[i] = dinv[i] * x[i] in fp16 for this bucket's 256 nodes.
// Degree accumulation uses u64 FIXED-POINT (w * 2^32) with NATIVE ds_add_u64 —
// f32 LDS atomicAdd compiles to a CAS retry loop on gfx950 (round-2 lesson).
__global__ void __launch_bounds__(1024) k_sort(const int* __restrict__ cursor,
                                               u64* __restrict__ binned,
                                               const float2* __restrict__ x2,
                                               float* __restrict__ dinv,
                                               __half2* __restrict__ xs2,
                                               int* __restrict__ off_g, int* __restrict__ len_g,
                                               int n) {
    __shared__ u64 srt[CAPC];        // 43.5 KB
    __shared__ int hist[256];
    __shared__ int noff[256];
    __shared__ int cur[256];
    __shared__ u64 degw64[256];
    __shared__ float dvS[256];

    int r = blockIdx.x, tid = threadIdx.x;
    if (tid < 256) { hist[tid] = 0; degw64[tid] = 0ULL; }
    __syncthreads();

    int cnt = min(cursor[r], CAPC);
    u64* B = binned + (size_t)r * CAPC;

    // pass A: histogram + weighted degree (u64 fixed point, native atomic)
    for (int i = tid; i < cnt; i += 1024) {
        u64 m = B[i];
        int dl = ((unsigned)m >> 17) & 255;
        atomicAdd(&hist[dl], 1);
        float w = __uint_as_float((unsigned)(m >> 32));
        atomicAdd(&degw64[dl], (u64)(w * 4294967296.0f));
    }
    __syncthreads();

    // wave 0: exclusive scan hist[256] -> noff
    if (tid < 64) {
        int s0 = hist[tid * 4], s1 = hist[tid * 4 + 1], s2 = hist[tid * 4 + 2], s3 = hist[tid * 4 + 3];
        int tot = s0 + s1 + s2 + s3;
        int scan = tot;
#pragma unroll
        for (int o = 1; o < 64; o <<= 1) {
            int v = __shfl_up(scan, o);
            if (tid >= o) scan += v;
        }
        int run = scan - tot;
        noff[tid * 4] = run; run += s0;
        noff[tid * 4 + 1] = run; run += s1;
        noff[tid * 4 + 2] = run; run += s2;
        noff[tid * 4 + 3] = run;
    }
    __syncthreads();

    if (tid < 256) {
        int node = r * 256 + tid;
        float deg = (float)degw64[tid] * 0x1p-32f;
        float dv = rsqrtf(1.0f + deg);
        if (node < n) {
            dinv[node] = dv;
            off_g[node] = r * CAPC + noff[tid];
            len_g[node] = hist[tid];
        }
        cur[tid] = noff[tid];
        dvS[tid] = dv;
    }
    __syncthreads();

    // pass B: ticket-place into sorted LDS order (global L2-hot re-read -> LDS)
    for (int i = tid; i < cnt; i += 1024) {
        u64 m = B[i];
        int dl = ((unsigned)m >> 17) & 255;
        int p = atomicAdd(&cur[dl], 1);
        srt[p] = (u64)((unsigned)m & 0x1FFFF) | (m & 0xFFFFFFFF00000000ULL);
    }
    __syncthreads();

    // coalesced in-place flush + xs build (independent streams)
    for (int i = tid; i < cnt; i += 1024) B[i] = srt[i];
    int nbase = r * 256;
    for (int i = tid; i < 256 * 32; i += 1024) {
        int nl = i >> 5, cp = i & 31;
        int node = nbase + nl;
        if (node < n) {
            float2 xv = x2[((size_t)node << 5) + cp];
            float dv = dvS[nl];
            xs2[((size_t)node << 5) + cp] = __floats2half2_rn(dv * xv.x, dv * xv.y);
        }
    }
}

// wave per node over CSR runs: agg = dd * (xs[d] + sum ew*xs[src]); ILP-16.
// Round-0 inner body (proven best across 5 variants). Block size 512 (8 waves):
// halves the number of short-lived blocks (25000 -> 12500) to cut block-turnover
// bubbles — counters showed 66% occupancy with VGPR=24/no-LDS (not resource-capped).
__global__ void __launch_bounds__(512) k_gather(const int* __restrict__ off_g, const int* __restrict__ len_g,
                                                const u64* __restrict__ csr, const float* __restrict__ dinv,
                                                const __half* __restrict__ xs,
                                                __half* __restrict__ aggh, int n) {
    int lane = threadIdx.x & 63;
    int wid = __builtin_amdgcn_readfirstlane(threadIdx.x >> 6);
    int d = blockIdx.x * 8 + wid;
    if (d >= n) return;
    int o0 = off_g[d], L = len_g[d];
    float dd = dinv[d];
    float acc[16];
#pragma unroll
    for (int j = 0; j < 16; j++) acc[j] = 0.f;
    acc[0] = (float)xs[((size_t)d << 6) + lane];   // self term (weight 1 in scaled space)

    for (int base = 0; base < L; base += 64) {
        int c = min(64, L - base);
        u64 m = (lane < c) ? csr[(size_t)(o0 + base) + lane] : 0;
        int s_l = (unsigned)m & 0x1FFFF;
        float w_l = __uint_as_float((unsigned)(m >> 32));
        int k = 0;
        for (; k + 16 <= c; k += 16) {
            int ss[16]; float ww[16], xr[16];
#pragma unroll
            for (int j = 0; j < 16; j++) { ss[j] = rli(s_l, k + j); ww[j] = rlf(w_l, k + j); }
#pragma unroll
            for (int j = 0; j < 16; j++) xr[j] = (float)xs[((size_t)ss[j] << 6) + lane];
#pragma unroll
            for (int j = 0; j < 16; j++) acc[j] = fmaf(ww[j], xr[j], acc[j]);
        }
        for (; k + 4 <= c; k += 4) {
            int ss[4]; float ww[4], xr[4];
#pragma unroll
            for (int j = 0; j < 4; j++) { ss[j] = rli(s_l, k + j); ww[j] = rlf(w_l, k + j); }
#pragma unroll
            for (int j = 0; j < 4; j++) xr[j] = (float)xs[((size_t)ss[j] << 6) + lane];
#pragma unroll
            for (int j = 0; j < 4; j++) acc[j] = fmaf(ww[j], xr[j], acc[j]);
        }
        for (; k < c; k++) {
            int s0 = rli(s_l, k);
            float w0 = rlf(w_l, k);
            acc[0] = fmaf(w0, (float)xs[((size_t)s0 << 6) + lane], acc[0]);
        }
    }
    float s = ((acc[0] + acc[1]) + (acc[2] + acc[3])) + ((acc[4] + acc[5]) + (acc[6] + acc[7]))
            + ((acc[8] + acc[9]) + (acc[10] + acc[11])) + ((acc[12] + acc[13]) + (acc[14] + acc[15]));
    aggh[((size_t)d << 7) + lane] = (__half)(dd * s);
}

// MFMA gate kernel (body unchanged, known-good); grid = one 64-node group per block
__global__ void __launch_bounds__(256, 2) k_node(
        const __half* __restrict__ aggh,
        const __half* __restrict__ B1f_g, const __half* __restrict__ B2f_g,
        const float* __restrict__ bias_g, const float* __restrict__ Whead,
        const float* __restrict__ bhead,
        float* __restrict__ out_head, float* __restrict__ out_h, int n) {

    __shared__ __half B1s[24576];
    __shared__ __half B2s[4096];
    __shared__ float biasS[192];
    __shared__ float whS[64];
    __shared__ __half hrb[4][16 * 72];

    int tid = threadIdx.x;
    {
        const uint4* s1 = (const uint4*)B1f_g; uint4* d1 = (uint4*)B1s;
        for (int i = tid; i < 3072; i += 256) d1[i] = s1[i];
        const uint4* s2 = (const uint4*)B2f_g; uint4* d2 = (uint4*)B2s;
        for (int i = tid; i < 512; i += 256) d2[i] = s2[i];
        if (tid < 192) biasS[tid] = bias_g[tid];
        if (tid < 64) whS[tid] = Whead[tid];
    }
    __syncthreads();

    int lane = tid & 63;
    int wave = tid >> 6;
    int quad = lane >> 4;
    int l15 = lane & 15;

    float bz4[4], br4[4], bh4[4], wh4[4];
#pragma unroll
    for (int nt = 0; nt < 4; nt++) {
        bz4[nt] = biasS[nt * 16 + l15];
        br4[nt] = biasS[64 + nt * 16 + l15];
        bh4[nt] = biasS[128 + nt * 16 + l15];
        wh4[nt] = whS[nt * 16 + l15];
    }
    float bhv = bhead[0];
    __half* myhr = &hrb[wave][0];
    const half8* B1v = (const half8*)B1s;
    const half8* B2v = (const half8*)B2s;

    int mbase = blockIdx.x * 64 + wave * 16;
    if (mbase < n) {
        const half8* arow = (const half8*)(aggh + (((size_t)(mbase + l15)) << 7) + (quad << 3));
        half8 a0 = arow[0], a1 = arow[4], a2 = arow[8], a3 = arow[12];

        f32x4 acc[12];
#pragma unroll
        for (int nt = 0; nt < 12; nt++) acc[nt] = (f32x4){0.f, 0.f, 0.f, 0.f};

#pragma unroll
        for (int nt = 0; nt < 12; nt++) {
            acc[nt] = __builtin_amdgcn_mfma_f32_16x16x32_f16(a0, B1v[(0 * 12 + nt) * 64 + lane], acc[nt], 0, 0, 0);
            acc[nt] = __builtin_amdgcn_mfma_f32_16x16x32_f16(a1, B1v[(1 * 12 + nt) * 64 + lane], acc[nt], 0, 0, 0);
            acc[nt] = __builtin_amdgcn_mfma_f32_16x16x32_f16(a2, B1v[(2 * 12 + nt) * 64 + lane], acc[nt], 0, 0, 0);
            acc[nt] = __builtin_amdgcn_mfma_f32_16x16x32_f16(a3, B1v[(3 * 12 + nt) * 64 + lane], acc[nt], 0, 0, 0);
        }

        float hv[4][4];
#pragma unroll
        for (int nt = 0; nt < 4; nt++)
#pragma unroll
            for (int r = 0; r < 4; r++)
                hv[nt][r] = (float)aggh[(((size_t)(mbase + quad * 4 + r)) << 7) + 64 + nt * 16 + l15];

        float Z[4][4];
#pragma unroll
        for (int nt = 0; nt < 4; nt++)
#pragma unroll
            for (int r = 0; r < 4; r++) {
                Z[nt][r] = sigm(acc[nt][r] + bz4[nt]);
                float R = sigm(acc[4 + nt][r] + br4[nt]);
                myhr[(quad * 4 + r) * 72 + nt * 16 + l15] = (__half)(hv[nt][r] * R);
            }
        __builtin_amdgcn_s_waitcnt(0);

        half8 a2f0 = *(const half8*)(myhr + l15 * 72 + quad * 8);
        half8 a2f1 = *(const half8*)(myhr + l15 * 72 + 32 + quad * 8);

#pragma unroll
        for (int nt = 0; nt < 4; nt++) {
            acc[8 + nt] = __builtin_amdgcn_mfma_f32_16x16x32_f16(a2f0, B2v[(0 * 4 + nt) * 64 + lane], acc[8 + nt], 0, 0, 0);
            acc[8 + nt] = __builtin_amdgcn_mfma_f32_16x16x32_f16(a2f1, B2v[(1 * 4 + nt) * 64 + lane], acc[8 + nt], 0, 0, 0);
        }

        float pr0 = 0.f, pr1 = 0.f, pr2 = 0.f, pr3 = 0.f;
#pragma unroll
        for (int nt = 0; nt < 4; nt++) {
#pragma unroll
            for (int r = 0; r < 4; r++) {
                float Ht = tanhfast(acc[8 + nt][r] + bh4[nt]);
                float z = Z[nt][r];
                float hn = z * hv[nt][r] + (1.f - z) * Ht;
                out_h[((size_t)(mbase + quad * 4 + r)) * 64 + nt * 16 + l15] = hn;
                float rv = fmaxf(hn, 0.f) * wh4[nt];
                if (r == 0) pr0 += rv; else if (r == 1) pr1 += rv; else if (r == 2) pr2 += rv; else pr3 += rv;
            }
        }
#pragma unroll
        for (int o = 1; o < 16; o <<= 1) {
            pr0 += __shfl_xor(pr0, o);
            pr1 += __shfl_xor(pr1, o);
            pr2 += __shfl_xor(pr2, o);
            pr3 += __shfl_xor(pr3, o);
        }
        if (l15 == 0) {
            out_head[mbase + quad * 4 + 0] = pr0 + bhv;
            out_head[mbase + quad * 4 + 1] = pr1 + bhv;
            out_head[mbase + quad * 4 + 2] = pr2 + bhv;
            out_head[mbase + quad * 4 + 3] = pr3 + bhv;
        }
    }
}

extern "C" void kernel_launch(void* const* d_in, const int* in_sizes, int n_in,
                              void* d_out, int out_size, void* d_ws, size_t ws_size,
                              hipStream_t stream) {
    const float* x     = (const float*)d_in[0];
    const int*   src   = (const int*)d_in[1];
    const int*   dst   = (const int*)d_in[2];
    const float* ew    = (const float*)d_in[3];
    const float* h     = (const float*)d_in[4];
    const float* Wcz   = (const float*)d_in[5];
    const float* bcz   = (const float*)d_in[6];
    const float* Wcr   = (const float*)d_in[7];
    const float* bcr   = (const float*)d_in[8];
    const float* Wch   = (const float*)d_in[9];
    const float* bch   = (const float*)d_in[10];
    const float* Wlz   = (const float*)d_in[11];
    const float* blz   = (const float*)d_in[12];
    const float* Wlr   = (const float*)d_in[13];
    const float* blr   = (const float*)d_in[14];
    const float* Wlh   = (const float*)d_in[15];
    const float* blh   = (const float*)d_in[16];
    const float* Whead = (const float*)d_in[17];
    const float* bhead = (const float*)d_in[18];

    int E = in_sizes[1];
    int n = in_sizes[4] / 64;                 // 100000 nodes
    int R = (n + 255) >> 8;                   // 391 buckets of 256 nodes

    // workspace layout
    __half* aggh = (__half*)d_ws;                        // n*128 fp16: [agg | h]
    __half* xs   = aggh + (size_t)n * 128;               // n*64 fp16 (dinv-scaled x)
    u64*   binned = (u64*)(xs + (size_t)n * 64);         // R*CAPC u64
    float* dinv  = (float*)(binned + (size_t)R * CAPC);  // n f32
    int*   off_g = (int*)(dinv + n);                     // n
    int*   len_g = off_g + n;                            // n
    int*   cursor = len_g + n;                           // 1024
    __half* B1f  = (__half*)(cursor + 1024);             // 24576 fp16
    __half* B2f  = B1f + 24576;                          // 4096 fp16
    float* bias  = (float*)(B2f + 4096);                 // 192 f32

    float* out_head = (float*)d_out;          // [n]
    float* out_h    = out_head + n;           // [n*64]

    int hq = n * 16;                          // float4 groups of h
    int nbB = (E + EPB - 1) / EPB;
    int gridPre = 113 + (hq + 255) / 256;

    k_pre<<<gridPre, 256, 0, stream>>>(Wcz, bcz, Wcr, bcr, Wch, bch,
                                       Wlz, blz, Wlr, blr, Wlh, blh,
                                       (const float4*)h, aggh, B1f, B2f, bias, cursor, hq);
    k_bin<<<nbB, 1024, 0, stream>>>(src, dst, ew, cursor, binned, E, R);
    k_sort<<<R, 1024, 0, stream>>>(cursor, binned, (const float2*)x, dinv,
                                   (__half2*)xs, off_g, len_g, n);
    k_gather<<<(n + 7) / 8, 512, 0, stream>>>(off_g, len_g, binned, dinv, xs, aggh, n);
    k_node<<<(n + 63) / 64, 256, 0, stream>>>(aggh, B1f, B2f, bias, Whead, bhead,
                                              out_head, out_h, n);
}

// Round 10
// 234.951 us; speedup vs baseline: 1.7618x; 1.0164x over previous
//
#include <hip/hip_runtime.h>
#include <hip/hip_fp16.h>
#include <stdint.h>

typedef unsigned long long u64;
typedef _Float16 half8 __attribute__((ext_vector_type(8)));
typedef float f32x4 __attribute__((ext_vector_type(4)));

#define EPB 6144      // edges staged per k_bin block
#define CAPC 5440     // bucket capacity (mean 4096 + huge margin)

__device__ __forceinline__ float sigm(float x) { return 1.0f / (1.0f + __expf(-x)); }
__device__ __forceinline__ float tanhfast(float x) { return 1.0f - 2.0f / (__expf(2.0f * x) + 1.0f); }
__device__ __forceinline__ int rli(int v, int k) { return __builtin_amdgcn_readlane(v, k); }
__device__ __forceinline__ float rlf(float v, int k) {
    return __int_as_float(__builtin_amdgcn_readlane(__float_as_int(v), k));
}

// Merged: fragment-packed weight build (blocks 0..112) + h->fp16 (blocks 113..) + cursor zero.
__global__ void k_pre(const float* __restrict__ Wcz, const float* __restrict__ bcz,
                      const float* __restrict__ Wcr, const float* __restrict__ bcr,
                      const float* __restrict__ Wch, const float* __restrict__ bch,
                      const float* __restrict__ Wlz, const float* __restrict__ blz,
                      const float* __restrict__ Wlr, const float* __restrict__ blr,
                      const float* __restrict__ Wlh, const float* __restrict__ blh,
                      const float4* __restrict__ h4, __half* __restrict__ aggh,
                      __half* __restrict__ B1f, __half* __restrict__ B2f,
                      float* __restrict__ bias, int* __restrict__ cursor, int hq) {
    int bid = blockIdx.x;
    if (bid < 113) {
        int tid = bid * 256 + threadIdx.x;
        if (tid < 1024) cursor[tid] = 0;
        if (tid < 24576) {
            int k = tid / 192, nc = tid % 192;
            int g = nc >> 6, j = nc & 63;
            const float* Wc = (g == 0) ? Wcz : (g == 1) ? Wcr : Wch;
            const float* Wl = (g == 0) ? Wlz : (g == 1) ? Wlr : Wlh;
            float v;
            if (k < 64) {
                float acc = 0.f;
                for (int m = 0; m < 64; m++) acc += Wc[k * 64 + m] * Wl[m * 64 + j];
                v = acc;
            } else {
                v = (g < 2) ? Wl[k * 64 + j] : 0.f;
            }
            int kt = k >> 5, nt = nc >> 4;
            int lane = (((k >> 3) & 3) << 4) | (nc & 15);
            B1f[(((kt * 12 + nt) * 64 + lane) << 3) + (k & 7)] = (__half)v;
        } else if (tid < 24576 + 4096) {
            int t = tid - 24576;
            int k = t >> 6, nc = t & 63;
            float v = Wlh[(64 + k) * 64 + nc];
            int kt = k >> 5, nt = nc >> 4;
            int lane = (((k >> 3) & 3) << 4) | (nc & 15);
            B2f[(((kt * 4 + nt) * 64 + lane) << 3) + (k & 7)] = (__half)v;
        } else if (tid < 24576 + 4096 + 192) {
            int t = tid - 24576 - 4096;
            int g = t >> 6, j = t & 63;
            const float* bc = (g == 0) ? bcz : (g == 1) ? bcr : bch;
            const float* Wl = (g == 0) ? Wlz : (g == 1) ? Wlr : Wlh;
            const float* bl = (g == 0) ? blz : (g == 1) ? blr : blh;
            float acc = bl[j];
            for (int m = 0; m < 64; m++) acc += bc[m] * Wl[m * 64 + j];
            bias[t] = acc;
        }
    } else {
        int i = (bid - 113) * 256 + threadIdx.x;
        if (i < hq) {
            float4 hv = h4[i];
            int elem = i * 4;
            int node = elem >> 6, c = elem & 63;
            __half2* ho = (__half2*)(aggh + (((size_t)node) << 7) + 64 + c);
            ho[0] = __floats2half2_rn(hv.x, hv.y);
            ho[1] = __floats2half2_rn(hv.z, hv.w);
        }
    }
}

// One-pass LDS-staged counting sort of edges into 256-node dst-buckets.
// rec u64: [63:32]=ew bits, [24:17]=dst&255, [16:0]=src
__global__ void __launch_bounds__(1024) k_bin(const int* __restrict__ src, const int* __restrict__ dst,
                                              const float* __restrict__ ew,
                                              int* __restrict__ cursor, u64* __restrict__ binned,
                                              int E, int R) {
    __shared__ u64 recs[EPB];        // 48 KB
    __shared__ int hist[512];
    __shared__ int loff[512];
    __shared__ int curL[512];
    __shared__ int gbase[512];

    int tid = threadIdx.x;
    if (tid < 512) hist[tid] = 0;
    __syncthreads();

    int base = blockIdx.x * EPB;
    int cntE = min(EPB, E - base);

    u64 myrec[6];
    int myr[6];
#pragma unroll
    for (int j = 0; j < 6; j++) {
        int idx = tid + j * 1024;
        if (idx < cntE) {
            int e = base + idx;
            int d = dst[e], s = src[e];
            float w = ew[e];
            int r = d >> 8;
            myr[j] = r;
            myrec[j] = (u64)((unsigned)s | ((unsigned)(d & 255) << 17)) | ((u64)__float_as_uint(w) << 32);
            atomicAdd(&hist[r], 1);
        } else myr[j] = -1;
    }
    __syncthreads();

    // wave 0: exclusive scan of hist[512] -> loff
    if (tid < 64) {
        int sums[8], tot = 0;
#pragma unroll
        for (int q = 0; q < 8; q++) { sums[q] = hist[tid * 8 + q]; tot += sums[q]; }
        int scan = tot;
#pragma unroll
        for (int o = 1; o < 64; o <<= 1) {
            int v = __shfl_up(scan, o);
            if (tid >= o) scan += v;
        }
        int run = scan - tot;   // exclusive
#pragma unroll
        for (int q = 0; q < 8; q++) { loff[tid * 8 + q] = run; run += sums[q]; }
    }
    if (tid < 512) curL[tid] = 0;
    if (tid < R) {
        int hcnt = hist[tid];
        if (hcnt > 0) gbase[tid] = tid * CAPC + atomicAdd(&cursor[tid], hcnt);
    }
    __syncthreads();

    // place into LDS, bucket-sorted
#pragma unroll
    for (int j = 0; j < 6; j++) {
        if (myr[j] >= 0) {
            int p = atomicAdd(&curL[myr[j]], 1);
            recs[loff[myr[j]] + p] = myrec[j];
        }
    }
    __syncthreads();

    // flush: wave w handles buckets w, w+16, ... with coalesced runs
    int wave = tid >> 6, lane = tid & 63;
    for (int r = wave; r < R; r += 16) {
        int len = hist[r];
        if (!len) continue;
        int gb = gbase[r], lo = loff[r];
        int capEnd = (r + 1) * CAPC;
        for (int i = lane; i < len; i += 64)
            if (gb + i < capEnd) binned[(size_t)(gb + i)] = recs[lo + i];
    }
}

// Per-bucket: histogram+degree -> scan -> dinv/off/len; ticket-sort to CSR in place;
// also builds xs[i] = dinv[i] * x[i] in fp16 for this bucket's 256 nodes.
// Degree accumulation uses u64 FIXED-POINT (w * 2^32) with NATIVE ds_add_u64 —
// f32 LDS atomicAdd compiles to a CAS retry loop on gfx950 (round-2 lesson).
__global__ void __launch_bounds__(1024) k_sort(const int* __restrict__ cursor,
                                               u64* __restrict__ binned,
                                               const float2* __restrict__ x2,
                                               float* __restrict__ dinv,
                                               __half2* __restrict__ xs2,
                                               int* __restrict__ off_g, int* __restrict__ len_g,
                                               int n) {
    __shared__ u64 srt[CAPC];        // 43.5 KB
    __shared__ int hist[256];
    __shared__ int noff[256];
    __shared__ int cur[256];
    __shared__ u64 degw64[256];
    __shared__ float dvS[256];

    int r = blockIdx.x, tid = threadIdx.x;
    if (tid < 256) { hist[tid] = 0; degw64[tid] = 0ULL; }
    __syncthreads();

    int cnt = min(cursor[r], CAPC);
    u64* B = binned + (size_t)r * CAPC;

    // pass A: histogram + weighted degree (u64 fixed point, native atomic)
    for (int i = tid; i < cnt; i += 1024) {
        u64 m = B[i];
        int dl = ((unsigned)m >> 17) & 255;
        atomicAdd(&hist[dl], 1);
        float w = __uint_as_float((unsigned)(m >> 32));
        atomicAdd(&degw64[dl], (u64)(w * 4294967296.0f));
    }
    __syncthreads();

    // wave 0: exclusive scan hist[256] -> noff
    if (tid < 64) {
        int s0 = hist[tid * 4], s1 = hist[tid * 4 + 1], s2 = hist[tid * 4 + 2], s3 = hist[tid * 4 + 3];
        int tot = s0 + s1 + s2 + s3;
        int scan = tot;
#pragma unroll
        for (int o = 1; o < 64; o <<= 1) {
            int v = __shfl_up(scan, o);
            if (tid >= o) scan += v;
        }
        int run = scan - tot;
        noff[tid * 4] = run; run += s0;
        noff[tid * 4 + 1] = run; run += s1;
        noff[tid * 4 + 2] = run; run += s2;
        noff[tid * 4 + 3] = run;
    }
    __syncthreads();

    if (tid < 256) {
        int node = r * 256 + tid;
        float deg = (float)degw64[tid] * 0x1p-32f;
        float dv = rsqrtf(1.0f + deg);
        if (node < n) {
            dinv[node] = dv;
            off_g[node] = r * CAPC + noff[tid];
            len_g[node] = hist[tid];
        }
        cur[tid] = noff[tid];
        dvS[tid] = dv;
    }
    __syncthreads();

    // pass B: ticket-place into sorted LDS order (global L2-hot re-read -> LDS)
    for (int i = tid; i < cnt; i += 1024) {
        u64 m = B[i];
        int dl = ((unsigned)m >> 17) & 255;
        int p = atomicAdd(&cur[dl], 1);
        srt[p] = (u64)((unsigned)m & 0x1FFFF) | (m & 0xFFFFFFFF00000000ULL);
    }
    __syncthreads();

    // coalesced in-place flush + xs build (independent streams)
    for (int i = tid; i < cnt; i += 1024) B[i] = srt[i];
    int nbase = r * 256;
    for (int i = tid; i < 256 * 32; i += 1024) {
        int nl = i >> 5, cp = i & 31;
        int node = nbase + nl;
        if (node < n) {
            float2 xv = x2[((size_t)node << 5) + cp];
            float dv = dvS[nl];
            xs2[((size_t)node << 5) + cp] = __floats2half2_rn(dv * xv.x, dv * xv.y);
        }
    }
}

// wave per node over CSR runs: agg = dd * (xs[d] + sum ew*xs[src]); ILP-16
// (exact round-0 structure: proven best across 6 restructure attempts —
// scalar-pipe, LDS-atomic, persistent-grid, NT-load, 512-thread all regressed)
__global__ void __launch_bounds__(256) k_gather(const int* __restrict__ off_g, const int* __restrict__ len_g,
                                                const u64* __restrict__ csr, const float* __restrict__ dinv,
                                                const __half* __restrict__ xs,
                                                __half* __restrict__ aggh, int n) {
    int lane = threadIdx.x & 63;
    int wid = __builtin_amdgcn_readfirstlane(threadIdx.x >> 6);
    int d = blockIdx.x * 4 + wid;
    if (d >= n) return;
    int o0 = off_g[d], L = len_g[d];
    float dd = dinv[d];
    float acc[16];
#pragma unroll
    for (int j = 0; j < 16; j++) acc[j] = 0.f;
    acc[0] = (float)xs[((size_t)d << 6) + lane];   // self term (weight 1 in scaled space)

    for (int base = 0; base < L; base += 64) {
        int c = min(64, L - base);
        u64 m = (lane < c) ? csr[(size_t)(o0 + base) + lane] : 0;
        int s_l = (unsigned)m & 0x1FFFF;
        float w_l = __uint_as_float((unsigned)(m >> 32));
        int k = 0;
        for (; k + 16 <= c; k += 16) {
            int ss[16]; float ww[16], xr[16];
#pragma unroll
            for (int j = 0; j < 16; j++) { ss[j] = rli(s_l, k + j); ww[j] = rlf(w_l, k + j); }
#pragma unroll
            for (int j = 0; j < 16; j++) xr[j] = (float)xs[((size_t)ss[j] << 6) + lane];
#pragma unroll
            for (int j = 0; j < 16; j++) acc[j] = fmaf(ww[j], xr[j], acc[j]);
        }
        for (; k + 4 <= c; k += 4) {
            int ss[4]; float ww[4], xr[4];
#pragma unroll
            for (int j = 0; j < 4; j++) { ss[j] = rli(s_l, k + j); ww[j] = rlf(w_l, k + j); }
#pragma unroll
            for (int j = 0; j < 4; j++) xr[j] = (float)xs[((size_t)ss[j] << 6) + lane];
#pragma unroll
            for (int j = 0; j < 4; j++) acc[j] = fmaf(ww[j], xr[j], acc[j]);
        }
        for (; k < c; k++) {
            int s0 = rli(s_l, k);
            float w0 = rlf(w_l, k);
            acc[0] = fmaf(w0, (float)xs[((size_t)s0 << 6) + lane], acc[0]);
        }
    }
    float s = ((acc[0] + acc[1]) + (acc[2] + acc[3])) + ((acc[4] + acc[5]) + (acc[6] + acc[7]))
            + ((acc[8] + acc[9]) + (acc[10] + acc[11])) + ((acc[12] + acc[13]) + (acc[14] + acc[15]));
    aggh[((size_t)d << 7) + lane] = (__half)(dd * s);
}

// MFMA gate kernel (body unchanged, known-good); grid = one 64-node group per block
__global__ void __launch_bounds__(256, 2) k_node(
        const __half* __restrict__ aggh,
        const __half* __restrict__ B1f_g, const __half* __restrict__ B2f_g,
        const float* __restrict__ bias_g, const float* __restrict__ Whead,
        const float* __restrict__ bhead,
        float* __restrict__ out_head, float* __restrict__ out_h, int n) {

    __shared__ __half B1s[24576];
    __shared__ __half B2s[4096];
    __shared__ float biasS[192];
    __shared__ float whS[64];
    __shared__ __half hrb[4][16 * 72];

    int tid = threadIdx.x;
    {
        const uint4* s1 = (const uint4*)B1f_g; uint4* d1 = (uint4*)B1s;
        for (int i = tid; i < 3072; i += 256) d1[i] = s1[i];
        const uint4* s2 = (const uint4*)B2f_g; uint4* d2 = (uint4*)B2s;
        for (int i = tid; i < 512; i += 256) d2[i] = s2[i];
        if (tid < 192) biasS[tid] = bias_g[tid];
        if (tid < 64) whS[tid] = Whead[tid];
    }
    __syncthreads();

    int lane = tid & 63;
    int wave = tid >> 6;
    int quad = lane >> 4;
    int l15 = lane & 15;

    float bz4[4], br4[4], bh4[4], wh4[4];
#pragma unroll
    for (int nt = 0; nt < 4; nt++) {
        bz4[nt] = biasS[nt * 16 + l15];
        br4[nt] = biasS[64 + nt * 16 + l15];
        bh4[nt] = biasS[128 + nt * 16 + l15];
        wh4[nt] = whS[nt * 16 + l15];
    }
    float bhv = bhead[0];
    __half* myhr = &hrb[wave][0];
    const half8* B1v = (const half8*)B1s;
    const half8* B2v = (const half8*)B2s;

    int mbase = blockIdx.x * 64 + wave * 16;
    if (mbase < n) {
        const half8* arow = (const half8*)(aggh + (((size_t)(mbase + l15)) << 7) + (quad << 3));
        half8 a0 = arow[0], a1 = arow[4], a2 = arow[8], a3 = arow[12];

        f32x4 acc[12];
#pragma unroll
        for (int nt = 0; nt < 12; nt++) acc[nt] = (f32x4){0.f, 0.f, 0.f, 0.f};

#pragma unroll
        for (int nt = 0; nt < 12; nt++) {
            acc[nt] = __builtin_amdgcn_mfma_f32_16x16x32_f16(a0, B1v[(0 * 12 + nt) * 64 + lane], acc[nt], 0, 0, 0);
            acc[nt] = __builtin_amdgcn_mfma_f32_16x16x32_f16(a1, B1v[(1 * 12 + nt) * 64 + lane], acc[nt], 0, 0, 0);
            acc[nt] = __builtin_amdgcn_mfma_f32_16x16x32_f16(a2, B1v[(2 * 12 + nt) * 64 + lane], acc[nt], 0, 0, 0);
            acc[nt] = __builtin_amdgcn_mfma_f32_16x16x32_f16(a3, B1v[(3 * 12 + nt) * 64 + lane], acc[nt], 0, 0, 0);
        }

        float hv[4][4];
#pragma unroll
        for (int nt = 0; nt < 4; nt++)
#pragma unroll
            for (int r = 0; r < 4; r++)
                hv[nt][r] = (float)aggh[(((size_t)(mbase + quad * 4 + r)) << 7) + 64 + nt * 16 + l15];

        float Z[4][4];
#pragma unroll
        for (int nt = 0; nt < 4; nt++)
#pragma unroll
            for (int r = 0; r < 4; r++) {
                Z[nt][r] = sigm(acc[nt][r] + bz4[nt]);
                float R = sigm(acc[4 + nt][r] + br4[nt]);
                myhr[(quad * 4 + r) * 72 + nt * 16 + l15] = (__half)(hv[nt][r] * R);
            }
        __builtin_amdgcn_s_waitcnt(0);

        half8 a2f0 = *(const half8*)(myhr + l15 * 72 + quad * 8);
        half8 a2f1 = *(const half8*)(myhr + l15 * 72 + 32 + quad * 8);

#pragma unroll
        for (int nt = 0; nt < 4; nt++) {
            acc[8 + nt] = __builtin_amdgcn_mfma_f32_16x16x32_f16(a2f0, B2v[(0 * 4 + nt) * 64 + lane], acc[8 + nt], 0, 0, 0);
            acc[8 + nt] = __builtin_amdgcn_mfma_f32_16x16x32_f16(a2f1, B2v[(1 * 4 + nt) * 64 + lane], acc[8 + nt], 0, 0, 0);
        }

        float pr0 = 0.f, pr1 = 0.f, pr2 = 0.f, pr3 = 0.f;
#pragma unroll
        for (int nt = 0; nt < 4; nt++) {
#pragma unroll
            for (int r = 0; r < 4; r++) {
                float Ht = tanhfast(acc[8 + nt][r] + bh4[nt]);
                float z = Z[nt][r];
                float hn = z * hv[nt][r] + (1.f - z) * Ht;
                out_h[((size_t)(mbase + quad * 4 + r)) * 64 + nt * 16 + l15] = hn;
                float rv = fmaxf(hn, 0.f) * wh4[nt];
                if (r == 0) pr0 += rv; else if (r == 1) pr1 += rv; else if (r == 2) pr2 += rv; else pr3 += rv;
            }
        }
#pragma unroll
        for (int o = 1; o < 16; o <<= 1) {
            pr0 += __shfl_xor(pr0, o);
            pr1 += __shfl_xor(pr1, o);
            pr2 += __shfl_xor(pr2, o);
            pr3 += __shfl_xor(pr3, o);
        }
        if (l15 == 0) {
            out_head[mbase + quad * 4 + 0] = pr0 + bhv;
            out_head[mbase + quad * 4 + 1] = pr1 + bhv;
            out_head[mbase + quad * 4 + 2] = pr2 + bhv;
            out_head[mbase + quad * 4 + 3] = pr3 + bhv;
        }
    }
}

extern "C" void kernel_launch(void* const* d_in, const int* in_sizes, int n_in,
                              void* d_out, int out_size, void* d_ws, size_t ws_size,
                              hipStream_t stream) {
    const float* x     = (const float*)d_in[0];
    const int*   src   = (const int*)d_in[1];
    const int*   dst   = (const int*)d_in[2];
    const float* ew    = (const float*)d_in[3];
    const float* h     = (const float*)d_in[4];
    const float* Wcz   = (const float*)d_in[5];
    const float* bcz   = (const float*)d_in[6];
    const float* Wcr   = (const float*)d_in[7];
    const float* bcr   = (const float*)d_in[8];
    const float* Wch   = (const float*)d_in[9];
    const float* bch   = (const float*)d_in[10];
    const float* Wlz   = (const float*)d_in[11];
    const float* blz   = (const float*)d_in[12];
    const float* Wlr   = (const float*)d_in[13];
    const float* blr   = (const float*)d_in[14];
    const float* Wlh   = (const float*)d_in[15];
    const float* blh   = (const float*)d_in[16];
    const float* Whead = (const float*)d_in[17];
    const float* bhead = (const float*)d_in[18];

    int E = in_sizes[1];
    int n = in_sizes[4] / 64;                 // 100000 nodes
    int R = (n + 255) >> 8;                   // 391 buckets of 256 nodes

    // workspace layout
    __half* aggh = (__half*)d_ws;                        // n*128 fp16: [agg | h]
    __half* xs   = aggh + (size_t)n * 128;               // n*64 fp16 (dinv-scaled x)
    u64*   binned = (u64*)(xs + (size_t)n * 64);         // R*CAPC u64
    float* dinv  = (float*)(binned + (size_t)R * CAPC);  // n f32
    int*   off_g = (int*)(dinv + n);                     // n
    int*   len_g = off_g + n;                            // n
    int*   cursor = len_g + n;                           // 1024
    __half* B1f  = (__half*)(cursor + 1024);             // 24576 fp16
    __half* B2f  = B1f + 24576;                          // 4096 fp16
    float* bias  = (float*)(B2f + 4096);                 // 192 f32

    float* out_head = (float*)d_out;          // [n]
    float* out_h    = out_head + n;           // [n*64]

    int hq = n * 16;                          // float4 groups of h
    int nbB = (E + EPB - 1) / EPB;
    int gridPre = 113 + (hq + 255) / 256;

    k_pre<<<gridPre, 256, 0, stream>>>(Wcz, bcz, Wcr, bcr, Wch, bch,
                                       Wlz, blz, Wlr, blr, Wlh, blh,
                                       (const float4*)h, aggh, B1f, B2f, bias, cursor, hq);
    k_bin<<<nbB, 1024, 0, stream>>>(src, dst, ew, cursor, binned, E, R);
    k_sort<<<R, 1024, 0, stream>>>(cursor, binned, (const float2*)x, dinv,
                                   (__half2*)xs, off_g, len_g, n);
    k_gather<<<(n + 3) / 4, 256, 0, stream>>>(off_g, len_g, binned, dinv, xs, aggh, n);
    k_node<<<(n + 63) / 64, 256, 0, stream>>>(aggh, B1f, B2f, bias, Whead, bhead,
                                              out_head, out_h, n);
}